// Round 16
// baseline (384.244 us; speedup 1.0000x reference)
//
#include <hip/hip_runtime.h>

// ---------------------------------------------------------------------------
// RWKV6 layer forward, MI355X. Round 16: gn_gate fused into wkv_pass3.
// A pass3 block (one batch,head,chunk; 128 threads = the head's 128 value
// channels) is exactly GroupNorm's reduction domain: keep oa[16] in regs,
// block-reduce mean/var, normalize + swish gate + bf16 store in-kernel.
// Removes gn_gate dispatch + ~40MB HBM traffic. GEMM frozen at v8.
// ---------------------------------------------------------------------------

#define DEVINL __device__ __forceinline__

constexpr int B_  = 8, T_ = 1024;
constexpr int BT_ = B_ * T_;          // 8192 tokens
constexpr float EPS_ = 1e-5f;
constexpr int CH_ = 16;               // WKV chunk length
constexpr int NC_ = T_ / CH_;         // 64 chunks per sequence

typedef __bf16 bf16x8 __attribute__((ext_vector_type(8)));
typedef float  f32x4  __attribute__((ext_vector_type(4)));

DEVINL unsigned short f2bs(float f) { // fp32 -> bf16 bits, RNE
  union { float f; unsigned int i; } c; c.f = f;
  unsigned int x = c.i;
  return (unsigned short)((x + 0x7fffu + ((x >> 16) & 1u)) >> 16);
}
DEVINL float b2f(unsigned short u) {
  union { unsigned int i; float f; } c; c.i = ((unsigned int)u) << 16; return c.f;
}

DEVINL float block_sum256(float v, float* sb) {
  for (int o = 32; o; o >>= 1) v += __shfl_down(v, o);
  int w = threadIdx.x >> 6;
  __syncthreads();
  if ((threadIdx.x & 63) == 0) sb[w] = v;
  __syncthreads();
  return sb[0] + sb[1] + sb[2] + sb[3];
}

// async global->LDS: 16B per lane, dest = ldsbase + lane*16 (wave-uniform base)
DEVINL void gload16(const unsigned short* gsrc, unsigned short* ldsbase) {
  __builtin_amdgcn_global_load_lds(
      (const __attribute__((address_space(1))) unsigned int*)gsrc,
      (__attribute__((address_space(3))) unsigned int*)ldsbase, 16, 0, 0);
}

// --------------------------- weight pack ------------------------------------
struct PackSeg { const float* src; int rows, cols, dst_rows; };
struct PackArgs { PackSeg s[12]; int base[13]; };

__global__ __launch_bounds__(256) void pack_kernel(PackArgs pa, unsigned short* dst)
{
  int i = blockIdx.x * 256 + threadIdx.x;
  if (i >= pa.base[12]) return;
  int k = 0;
  while (i >= pa.base[k + 1]) k++;
  int loc = i - pa.base[k];
  PackSeg s = pa.s[k];
  int r = loc / s.cols, c = loc - r * s.cols;
  float v = (r < s.rows) ? s.src[(size_t)r * s.cols + c] : 0.f;
  dst[i] = f2bs(v);
}

// --------------------------- LN kernels ------------------------------------
__global__ __launch_bounds__(256) void ln2_kernel(
    const float* __restrict__ x,
    const float* __restrict__ pg, const float* __restrict__ pb,
    const float* __restrict__ ag, const float* __restrict__ ab,
    float* __restrict__ x0, unsigned short* __restrict__ h)
{
  __shared__ float sb[4];
  size_t base = (size_t)blockIdx.x * 512;
  int tid = threadIdx.x;
  float v0 = x[base + tid], v1 = x[base + 256 + tid];
  float m = block_sum256(v0 + v1, sb) * (1.f / 512.f);
  float d0 = v0 - m, d1 = v1 - m;
  float var = block_sum256(d0 * d0 + d1 * d1, sb) * (1.f / 512.f);
  float rs = rsqrtf(var + EPS_);
  float a0 = d0 * rs * pg[tid]       + pb[tid];
  float a1 = d1 * rs * pg[tid + 256] + pb[tid + 256];
  x0[base + tid] = a0; x0[base + 256 + tid] = a1;
  float m2 = block_sum256(a0 + a1, sb) * (1.f / 512.f);
  float e0 = a0 - m2, e1 = a1 - m2;
  float var2 = block_sum256(e0 * e0 + e1 * e1, sb) * (1.f / 512.f);
  float rs2 = rsqrtf(var2 + EPS_);
  h[base + tid]       = f2bs(e0 * rs2 * ag[tid]       + ab[tid]);
  h[base + 256 + tid] = f2bs(e1 * rs2 * ag[tid + 256] + ab[tid + 256]);
}

__global__ __launch_bounds__(256) void ln1_kernel(
    const float* __restrict__ in,
    const float* __restrict__ g, const float* __restrict__ b,
    float* __restrict__ out)
{
  __shared__ float sb[4];
  size_t base = (size_t)blockIdx.x * 512;
  int tid = threadIdx.x;
  float v0 = in[base + tid], v1 = in[base + 256 + tid];
  float m = block_sum256(v0 + v1, sb) * (1.f / 512.f);
  float d0 = v0 - m, d1 = v1 - m;
  float var = block_sum256(d0 * d0 + d1 * d1, sb) * (1.f / 512.f);
  float rs = rsqrtf(var + EPS_);
  out[base + tid]       = d0 * rs * g[tid]       + b[tid];
  out[base + 256 + tid] = d1 * rs * g[tid + 256] + b[tid + 256];
}

// --------------------------- mix kernels ------------------------------------
__global__ __launch_bounds__(256) void ymix_kernel(
    const unsigned short* __restrict__ h, const float* __restrict__ mu,
    unsigned short* __restrict__ y, unsigned short* __restrict__ dl)
{
  int t = blockIdx.x, tid = threadIdx.x, tt = t & (T_ - 1);
  size_t base = (size_t)t * 512;
  for (int c = tid; c < 512; c += 256) {
    float cur  = b2f(h[base + c]);
    float prev = tt ? b2f(h[base - 512 + c]) : 0.f;
    float d = prev - cur;
    dl[base + c] = f2bs(d);
    y[base + c] = f2bs(cur + d * mu[c]);
  }
}

__global__ __launch_bounds__(256) void ffnmix_kernel(
    const float* __restrict__ hf, const float* __restrict__ fkmu,
    const float* __restrict__ frmu,
    unsigned short* __restrict__ mfk, unsigned short* __restrict__ mfr)
{
  int t = blockIdx.x, tid = threadIdx.x, tt = t & (T_ - 1);
  size_t base = (size_t)t * 512;
  for (int c = tid; c < 512; c += 256) {
    float cur  = hf[base + c];
    float prev = tt ? hf[base - 512 + c] : 0.f;
    float d = prev - cur;
    mfk[base + c] = f2bs(cur + d * fkmu[c]);
    mfr[base + c] = f2bs(cur + d * frmu[c]);
  }
}

// --------------------------- MFMA GEMM v8 -----------------------------------
enum { EP_NONE_F32 = 0, EP_NONE_BF16 = 1, EP_TANH_BF16 = 2, EP_EXPEXP_F32 = 3,
       EP_RES_F32 = 4, EP_RELU2_BF16 = 5, EP_OUT2_F32 = 6, EP_XMIX_BF16 = 7 };

struct GemmDesc {
  const unsigned short* A; const unsigned short* W; void* C;
  const void* bias; const void* aux1; const void* aux2;
  int N, K, lda, ldw, ldc, epi;
};
template <int NG> struct GD { GemmDesc d[NG]; };

template <int BM, int BN, int NG>
__global__ __launch_bounds__(256) void mgemm(GD<NG> p)
{
  GemmDesc dd = p.d[blockIdx.z];
  int n0 = blockIdx.y * BN;
  if (n0 >= dd.N) return;
  int m0 = blockIdx.x * BM;
  constexpr int MFR = BM / 32, NFR = BN / 32;
  constexpr int AIS = BM / 64, WIS = BN / 64;      // gload issues per wave
  constexpr int NLD = AIS + WIS;                   // loads per tile per wave
  __shared__ unsigned short LDSbuf[3 * (BM + BN) * 32];
  unsigned short* AsBase = LDSbuf;                 // [3][BM*32]
  unsigned short* WsBase = LDSbuf + 3 * BM * 32;   // [3][BN*32]
  int tid = threadIdx.x, lane = tid & 63, wid = tid >> 6;
  int wm = wid >> 1, wn = wid & 1, lrow = lane & 15, lkg = lane >> 4;
  int XL = (lrow & 3) ^ ((lrow >> 2) & 3);         // read-side XOR term

  const unsigned short* aSrc[AIS]; int aOff[AIS];
#pragma unroll
  for (int i = 0; i < AIS; i++) {
    int u = i * 256 + wid * 64 + lane;
    int row = u >> 2;
    int kg = (u & 3) ^ (row & 3) ^ ((row >> 2) & 3);
    aSrc[i] = dd.A + (size_t)(m0 + row) * dd.lda + kg * 8;
    aOff[i] = (i * 256 + wid * 64) * 8;
  }
  const unsigned short* wSrc[WIS]; int wOff[WIS];
#pragma unroll
  for (int i = 0; i < WIS; i++) {
    int u = i * 256 + wid * 64 + lane;
    int row = u >> 2;
    int kg = (u & 3) ^ (row & 3) ^ ((row >> 2) & 3);
    wSrc[i] = dd.W + (size_t)(n0 + row) * dd.ldw + kg * 8;
    wOff[i] = (i * 256 + wid * 64) * 8;
  }

  f32x4 acc[MFR][NFR];
#pragma unroll
  for (int mf = 0; mf < MFR; mf++)
#pragma unroll
    for (int nf = 0; nf < NFR; nf++) acc[mf][nf] = (f32x4){0.f, 0.f, 0.f, 0.f};

  int nt = dd.K >> 5;
#pragma unroll
  for (int i = 0; i < AIS; i++) gload16(aSrc[i], AsBase + aOff[i]);
#pragma unroll
  for (int i = 0; i < WIS; i++) gload16(wSrc[i], WsBase + wOff[i]);
  if (nt > 1) {
#pragma unroll
    for (int i = 0; i < AIS; i++) gload16(aSrc[i] + 32, AsBase + BM * 32 + aOff[i]);
#pragma unroll
    for (int i = 0; i < WIS; i++) gload16(wSrc[i] + 32, WsBase + BN * 32 + wOff[i]);
  }

  int cur = 0, pf = 2;                    // compute buffer / next fill buffer
  for (int t = 0; t < nt; ++t) {
    if (t + 2 < nt) {
      int kb2 = (t + 2) << 5;
      unsigned short* aD = AsBase + pf * (BM * 32);
      unsigned short* wD = WsBase + pf * (BN * 32);
#pragma unroll
      for (int i = 0; i < AIS; i++) gload16(aSrc[i] + kb2, aD + aOff[i]);
#pragma unroll
      for (int i = 0; i < WIS; i++) gload16(wSrc[i] + kb2, wD + wOff[i]);
      pf = (pf == 2) ? 0 : pf + 1;
      if constexpr (NLD == 4) asm volatile("s_waitcnt vmcnt(8)" ::: "memory");
      else                    asm volatile("s_waitcnt vmcnt(4)" ::: "memory");
    } else if (t + 1 < nt) {
      if constexpr (NLD == 4) asm volatile("s_waitcnt vmcnt(4)" ::: "memory");
      else                    asm volatile("s_waitcnt vmcnt(2)" ::: "memory");
    } else {
      asm volatile("s_waitcnt vmcnt(0)" ::: "memory");
    }
    __builtin_amdgcn_sched_barrier(0);
    __builtin_amdgcn_s_barrier();         // tile t's LDS complete, all waves

    const unsigned short* AsB = AsBase + cur * (BM * 32);
    const unsigned short* WsB = WsBase + cur * (BN * 32);
    bf16x8 bfrag[NFR];
#pragma unroll
    for (int nf = 0; nf < NFR; nf++) {
      int row = (wn * NFR + nf) * 16 + lrow;
      bfrag[nf] = *(const bf16x8*)&WsB[(row * 4 + (lkg ^ XL)) * 8];
    }
#pragma unroll
    for (int mf = 0; mf < MFR; mf++) {
      int row = (wm * MFR + mf) * 16 + lrow;
      bf16x8 afrag = *(const bf16x8*)&AsB[(row * 4 + (lkg ^ XL)) * 8];
#pragma unroll
      for (int nf = 0; nf < NFR; nf++)
        acc[mf][nf] = __builtin_amdgcn_mfma_f32_16x16x32_bf16(
            bfrag[nf], afrag, acc[mf][nf], 0, 0, 0);   // D rows = n
    }
    __builtin_amdgcn_sched_barrier(0);
    __builtin_amdgcn_s_barrier();         // all waves done reading cur
    cur = (cur == 2) ? 0 : cur + 1;
  }

  bool bf16out = (dd.epi == EP_NONE_BF16 || dd.epi == EP_TANH_BF16 ||
                  dd.epi == EP_RELU2_BF16 || dd.epi == EP_XMIX_BF16);
  if (!bf16out) {
#pragma unroll
    for (int mf = 0; mf < MFR; mf++) {
#pragma unroll
      for (int nf = 0; nf < NFR; nf++) {
        int m  = m0 + wm * (MFR * 16) + mf * 16 + lrow;
        int nb = n0 + wn * (NFR * 16) + nf * 16 + lkg * 4;
        size_t off = (size_t)m * dd.ldc + nb;
        float c0 = acc[mf][nf][0], c1 = acc[mf][nf][1];
        float c2 = acc[mf][nf][2], c3 = acc[mf][nf][3];
        switch (dd.epi) {
          case EP_NONE_F32: {
            f32x4 v = {c0, c1, c2, c3};
            *(f32x4*)((float*)dd.C + off) = v; break;
          }
          case EP_EXPEXP_F32: {
            const float* bi = (const float*)dd.bias;
            f32x4 v = {expf(-expf(c0 + bi[nb + 0])), expf(-expf(c1 + bi[nb + 1])),
                       expf(-expf(c2 + bi[nb + 2])), expf(-expf(c3 + bi[nb + 3]))};
            *(f32x4*)((float*)dd.C + off) = v; break;
          }
          case EP_RES_F32: {
            f32x4 a = *(const f32x4*)((const float*)dd.aux1 + off);
            f32x4 v = {c0 + a[0], c1 + a[1], c2 + a[2], c3 + a[3]};
            *(f32x4*)((float*)dd.C + off) = v; break;
          }
          case EP_OUT2_F32: {
            f32x4 rs = *(const f32x4*)((const float*)dd.aux1 + off);
            f32x4 fr = *(const f32x4*)((const float*)dd.aux2 + off);
            f32x4 v = {rs[0] + (1.f / (1.f + expf(-fr[0]))) * c0,
                       rs[1] + (1.f / (1.f + expf(-fr[1]))) * c1,
                       rs[2] + (1.f / (1.f + expf(-fr[2]))) * c2,
                       rs[3] + (1.f / (1.f + expf(-fr[3]))) * c3};
            *(f32x4*)((float*)dd.C + off) = v; break;
          }
        }
      }
    }
    return;
  }

  __syncthreads();                         // staging buffers fully dead
  unsigned short* Cs = LDSbuf;             // BM*BN shorts
#pragma unroll
  for (int mf = 0; mf < MFR; mf++) {
#pragma unroll
    for (int nf = 0; nf < NFR; nf++) {
      int mloc = wm * (MFR * 16) + mf * 16 + lrow;
      int nbl  = wn * (NFR * 16) + nf * 16 + lkg * 4;
      int m = m0 + mloc, nb = n0 + nbl;
      size_t off = (size_t)m * dd.ldc + nb;
      float c0 = acc[mf][nf][0], c1 = acc[mf][nf][1];
      float c2 = acc[mf][nf][2], c3 = acc[mf][nf][3];
      uint2 u;
      switch (dd.epi) {
        case EP_NONE_BF16:
          u.x = f2bs(c0) | ((unsigned)f2bs(c1) << 16);
          u.y = f2bs(c2) | ((unsigned)f2bs(c3) << 16);
          break;
        case EP_TANH_BF16:
          u.x = f2bs(tanhf(c0)) | ((unsigned)f2bs(tanhf(c1)) << 16);
          u.y = f2bs(tanhf(c2)) | ((unsigned)f2bs(tanhf(c3)) << 16);
          break;
        case EP_RELU2_BF16: {
          c0 = fmaxf(c0, 0.f); c1 = fmaxf(c1, 0.f);
          c2 = fmaxf(c2, 0.f); c3 = fmaxf(c3, 0.f);
          u.x = f2bs(c0 * c0) | ((unsigned)f2bs(c1 * c1) << 16);
          u.y = f2bs(c2 * c2) | ((unsigned)f2bs(c3 * c3) << 16);
          break;
        }
        default: { // EP_XMIX_BF16
          const float* bi = (const float*)dd.bias;
          uint2 hv = *(const uint2*)((const unsigned short*)dd.aux1 + off);
          uint2 dv = *(const uint2*)((const unsigned short*)dd.aux2 + off);
          const unsigned short* hu = (const unsigned short*)&hv;
          const unsigned short* du = (const unsigned short*)&dv;
          float r0 = b2f(hu[0]) + b2f(du[0]) * (c0 + bi[nb + 0]);
          float r1 = b2f(hu[1]) + b2f(du[1]) * (c1 + bi[nb + 1]);
          float r2 = b2f(hu[2]) + b2f(du[2]) * (c2 + bi[nb + 2]);
          float r3 = b2f(hu[3]) + b2f(du[3]) * (c3 + bi[nb + 3]);
          u.x = f2bs(r0) | ((unsigned)f2bs(r1) << 16);
          u.y = f2bs(r2) | ((unsigned)f2bs(r3) << 16);
          break;
        }
      }
      int col4 = (nbl >> 2) ^ ((mloc & 7) << 1);   // even XOR: keeps 16B pairs
      *(uint2*)&Cs[mloc * BN + col4 * 4] = u;
    }
  }
  __syncthreads();
  constexpr int JW = BN / 8;               // 16B units per row
  constexpr int UNITS = BM * JW;
  for (int it = tid; it < UNITS; it += 256) {
    int row = it / JW, j = it - row * JW;
    int e = (row & 7) << 1;
    int4 vv = *(const int4*)&Cs[row * BN + (((2 * j) ^ e) << 2)];
    *(int4*)((unsigned short*)dd.C + (size_t)(m0 + row) * dd.ldc + n0 + j * 8) = vv;
  }
}

// --------------------------- WKV 3-pass chunked scan (CH=16) ----------------
__global__ __launch_bounds__(128) void wkv_pass1(
    const unsigned short* __restrict__ k, const float* __restrict__ ew,
    const unsigned short* __restrict__ v, unsigned short* __restrict__ Sl,
    float* __restrict__ Dp)
{
  __shared__ float kL[CH_][64], eL[CH_][64];
  int blk = blockIdx.x;
  int c = blk & (NC_ - 1), bh = blk >> 6;
  int b = bh >> 2, hh = bh & 3;
  int tid = threadIdx.x;
  size_t tbase = (size_t)b * T_ + (size_t)c * CH_;
  for (int idx = tid; idx < CH_ * 64; idx += 128) {
    int s = idx >> 6, j = idx & 63;
    size_t g = (tbase + s) * 256 + hh * 64 + j;
    kL[s][j] = b2f(k[g]); eL[s][j] = ew[g];
  }
  __syncthreads();
  float S[64];
#pragma unroll
  for (int j = 0; j < 64; j++) S[j] = 0.f;
  for (int s = 0; s < CH_; s++) {
    float vv = b2f(v[(tbase + s) * 512 + hh * 128 + tid]);
    const float4* e4p = (const float4*)&eL[s][0];
    const float4* k4p = (const float4*)&kL[s][0];
#pragma unroll
    for (int q = 0; q < 16; q++) {
      float4 e4 = e4p[q], k4 = k4p[q];
      S[4 * q + 0] = e4.x * S[4 * q + 0] + k4.x * vv;
      S[4 * q + 1] = e4.y * S[4 * q + 1] + k4.y * vv;
      S[4 * q + 2] = e4.z * S[4 * q + 2] + k4.z * vv;
      S[4 * q + 3] = e4.w * S[4 * q + 3] + k4.w * vv;
    }
  }
  size_t sbase = (size_t)blk * 8192;
#pragma unroll
  for (int j = 0; j < 64; j++) Sl[sbase + j * 128 + tid] = f2bs(S[j]);
  if (tid < 64) {
    float d = 1.f;
    for (int s = 0; s < CH_; s++) d *= eL[s][tid];
    Dp[(size_t)blk * 64 + tid] = d;
  }
}

__global__ __launch_bounds__(256) void wkv_scan(
    const unsigned short* __restrict__ Sl, const float* __restrict__ Dp,
    unsigned short* __restrict__ Ss)
{
  int e = blockIdx.x * 256 + threadIdx.x;
  int bh = e >> 13; int kv = e & 8191; int j = kv >> 7;
  float run = 0.f;
  for (int c = 0; c < NC_; c++) {
    size_t base = (size_t)bh * NC_ + c;
    Ss[base * 8192 + kv] = f2bs(run);
    run = Dp[base * 64 + j] * run + b2f(Sl[base * 8192 + kv]);
  }
}

// pass3: replay chunk; rbk in-kernel; GroupNorm+swish gate fused (block =
// one head's 128 channels = GN reduction domain). Emits bf16 gated output.
__global__ __launch_bounds__(128) void wkv_pass3(
    const unsigned short* __restrict__ r, const unsigned short* __restrict__ k,
    const float* __restrict__ ew, const unsigned short* __restrict__ v,
    const float* __restrict__ bonus, const unsigned short* __restrict__ Ss,
    const unsigned short* __restrict__ g,
    const float* __restrict__ gg, const float* __restrict__ gb,
    unsigned short* __restrict__ obf)
{
  __shared__ float rL[CH_][64], kL[CH_][64], eL[CH_][64], rbL[CH_];
  __shared__ float sums[CH_][2], sqs[CH_][2];
  int blk = blockIdx.x;
  int c = blk & (NC_ - 1), bh = blk >> 6;
  int b = bh >> 2, hh = bh & 3;
  int tid = threadIdx.x;
  size_t tbase = (size_t)b * T_ + (size_t)c * CH_;
  for (int idx = tid; idx < CH_ * 64; idx += 128) {
    int s = idx >> 6, j = idx & 63;
    size_t gg2 = (tbase + s) * 256 + hh * 64 + j;
    rL[s][j] = b2f(r[gg2]); kL[s][j] = b2f(k[gg2]); eL[s][j] = ew[gg2];
  }
  __syncthreads();
  {
    // rbk: 8 lanes per token s
    int s = tid >> 3, part = tid & 7;
    float acc = 0.f;
#pragma unroll
    for (int q = 0; q < 8; q++) {
      int j = part * 8 + q;
      acc += rL[s][j] * kL[s][j] * bonus[hh * 64 + j];
    }
    acc += __shfl_down(acc, 4);
    acc += __shfl_down(acc, 2);
    acc += __shfl_down(acc, 1);
    if (part == 0) rbL[s] = acc;
  }
  __syncthreads();
  float S[64];
  size_t sbase = (size_t)blk * 8192;
#pragma unroll
  for (int j = 0; j < 64; j++) S[j] = b2f(Ss[sbase + j * 128 + tid]);
  float oa[CH_];
#pragma unroll
  for (int s = 0; s < CH_; s++) {
    float vv = b2f(v[(tbase + s) * 512 + hh * 128 + tid]);
    float o = rbL[s] * vv;
    const float4* r4p = (const float4*)&rL[s][0];
    const float4* e4p = (const float4*)&eL[s][0];
    const float4* k4p = (const float4*)&kL[s][0];
#pragma unroll
    for (int q = 0; q < 16; q++) {
      float4 r4 = r4p[q], e4 = e4p[q], k4 = k4p[q];
      o += r4.x * S[4 * q + 0] + r4.y * S[4 * q + 1]
         + r4.z * S[4 * q + 2] + r4.w * S[4 * q + 3];
      S[4 * q + 0] = e4.x * S[4 * q + 0] + k4.x * vv;
      S[4 * q + 1] = e4.y * S[4 * q + 1] + k4.y * vv;
      S[4 * q + 2] = e4.z * S[4 * q + 2] + k4.z * vv;
      S[4 * q + 3] = e4.w * S[4 * q + 3] + k4.w * vv;
    }
    oa[s] = o;
    // per-token (sum, sumsq) reduce across this wave (64 lanes)
    float sm = o, sq = o * o;
#pragma unroll
    for (int off2 = 32; off2; off2 >>= 1) {
      sm += __shfl_down(sm, off2);
      sq += __shfl_down(sq, off2);
    }
    if ((tid & 63) == 0) { sums[s][tid >> 6] = sm; sqs[s][tid >> 6] = sq; }
  }
  __syncthreads();
  int ch = hh * 128 + tid;
  float gam = gg[ch], bet = gb[ch];
#pragma unroll
  for (int s = 0; s < CH_; s++) {
    float m = (sums[s][0] + sums[s][1]) * (1.f / 128.f);
    float var = (sqs[s][0] + sqs[s][1]) * (1.f / 128.f) - m * m;
    float nrm = (oa[s] - m) * rsqrtf(var + EPS_);
    float gv = b2f(g[(tbase + s) * 512 + ch]);
    float sw = gv * (1.f / (1.f + expf(-gv)));
    obf[(tbase + s) * 512 + ch] = f2bs((nrm * gam + bet) * sw);
  }
}

// ---------------------------------------------------------------------------
extern "C" void kernel_launch(void* const* d_in, const int* in_sizes, int n_in,
                              void* d_out, int out_size, void* d_ws, size_t ws_size,
                              hipStream_t stream) {
  (void)in_sizes; (void)n_in; (void)out_size; (void)ws_size;
  const float* x        = (const float*)d_in[0];
  const float* pre_g    = (const float*)d_in[1];
  const float* pre_b    = (const float*)d_in[2];
  const float* attn_g   = (const float*)d_in[3];
  const float* attn_b   = (const float*)d_in[4];
  const float* ffn_g    = (const float*)d_in[5];
  const float* ffn_b    = (const float*)d_in[6];
  const float* xproj_mu = (const float*)d_in[7];
  const float* xproj_w1 = (const float*)d_in[8];
  const float* xproj_w2 = (const float*)d_in[9];
  const float* x_bias   = (const float*)d_in[10];
  const float* r_W      = (const float*)d_in[11];
  const float* w_W1     = (const float*)d_in[12];
  const float* w_W2     = (const float*)d_in[13];
  const float* w_b      = (const float*)d_in[14];
  const float* k_W      = (const float*)d_in[15];
  const float* v_W      = (const float*)d_in[16];
  const float* g_W      = (const float*)d_in[17];
  const float* bonus    = (const float*)d_in[18];
  const float* gnorm_g  = (const float*)d_in[19];
  const float* gnorm_b  = (const float*)d_in[20];
  const float* o_W      = (const float*)d_in[21];
  const float* fk_mu    = (const float*)d_in[22];
  const float* fk_W     = (const float*)d_in[23];
  const float* fv_W     = (const float*)d_in[24];
  const float* fr_mu    = (const float*)d_in[25];
  const float* fr_W     = (const float*)d_in[26];

  const size_t BTH = (size_t)BT_ * 512;  // 4,194,304
  size_t cur = 0;
  auto alloc = [&](size_t bytes) { void* p = (char*)d_ws + cur; cur += (bytes + 255) & ~(size_t)255; return p; };
  float*          x0    = (float*)alloc(BTH * 4);
  unsigned short* hbufb = (unsigned short*)alloc(BTH * 2);
  unsigned short* m5b   = (unsigned short*)alloc(5 * BTH * 2);   // 40MB
  unsigned short* rbuf  = (unsigned short*)alloc((size_t)BT_ * 256 * 4);
  unsigned short* kbuf  = (unsigned short*)alloc((size_t)BT_ * 256 * 4);
  float*          ebuf  = (float*)alloc((size_t)BT_ * 256 * 4);
  unsigned short* vbuf  = (unsigned short*)alloc(BTH * 4);
  unsigned short* gbuf  = (unsigned short*)alloc(BTH * 4);
  unsigned short* wtmpb = (unsigned short*)alloc((size_t)BT_ * 128 * 2);
  unsigned short* Sl    = (unsigned short*)alloc((size_t)2048 * 8192 * 2);
  unsigned short* Ss    = (unsigned short*)alloc((size_t)2048 * 8192 * 2);
  float*          Dp    = (float*)alloc((size_t)2048 * 64 * 4);
  float*          res   = (float*)alloc(BTH * 4);
  unsigned short* wpack = (unsigned short*)alloc((size_t)2621440 * 2);
  // aliases (occupant dead before writer runs):
  unsigned short* ybufb = rbuf;
  unsigned short* dlb   = vbuf;
  unsigned short* z5b   = gbuf;
  unsigned short* obf16 = (unsigned short*)ebuf;   // ebuf dead after pass3
  float*          hf    = x0;
  unsigned short* mfk   = rbuf;
  unsigned short* mfr   = kbuf;
  unsigned short* kkb   = Sl;
  float*          frtmp = (float*)vbuf;

  PackArgs pa;
  int off = 0, seg = 0;
  auto addseg = [&](const float* src, int rows, int cols, int dst_rows) {
    pa.s[seg] = {src, rows, cols, dst_rows};
    pa.base[seg] = off; off += dst_rows * cols; seg++;
  };
  addseg(xproj_w1, 160, 512, 192);   int o_w1p = pa.base[0];
  addseg(w_W1,      64, 512, 128);   int o_wW1 = pa.base[1];
  addseg(r_W,      256, 512, 256);   int o_rW  = pa.base[2];
  addseg(k_W,      256, 512, 256);   int o_kW  = pa.base[3];
  addseg(v_W,      512, 512, 512);   int o_vW  = pa.base[4];
  addseg(g_W,      512, 512, 512);   int o_gW  = pa.base[5];
  addseg(o_W,      512, 512, 512);   int o_oW  = pa.base[6];
  addseg(fk_W,    1024, 512, 1024);  int o_fkW = pa.base[7];
  addseg(fv_W,     512, 1024, 512);  int o_fvW = pa.base[8];
  addseg(fr_W,     512, 512, 512);   int o_frW = pa.base[9];
  addseg(w_W2,     256, 64, 256);    int o_wW2 = pa.base[10];
  addseg(xproj_w2, 512, 160, 512);   int o_xw2 = pa.base[11];
  pa.base[12] = off;

  pack_kernel<<<(off + 255) / 256, 256, 0, stream>>>(pa, wpack);
  ln2_kernel<<<BT_, 256, 0, stream>>>(x, pre_g, pre_b, attn_g, attn_b, x0, hbufb);
  ymix_kernel<<<BT_, 256, 0, stream>>>(hbufb, xproj_mu, ybufb, dlb);

  auto solo = [&](const unsigned short* A, const unsigned short* W, void* C,
                  const void* bias, const void* a1, const void* a2,
                  int N, int K, int lda, int ldw, int ldc, int epi) {
    GD<1> g; g.d[0] = {A, W, C, bias, a1, a2, N, K, lda, ldw, ldc, epi};
    mgemm<64, 64, 1><<<dim3(128, (N + 63) / 64, 1), 256, 0, stream>>>(g);
  };

  // z5 = tanh(Y @ W1p^T), N=192
  solo(ybufb, wpack + o_w1p, z5b, nullptr, nullptr, nullptr,
       192, 512, 512, 512, 192, EP_TANH_BF16);

  // xmix as grouped GEMM (K=32), LDS-staged EP_XMIX_BF16 epilogue
  {
    GD<5> g;
    for (int n = 0; n < 5; n++)
      g.d[n] = {z5b + n * 32, wpack + o_xw2 + n * 32, m5b + (size_t)n * BTH,
                x_bias + n * 512, hbufb, dlb, 512, 32, 192, 160, 512, EP_XMIX_BF16};
    mgemm<128, 128, 5><<<dim3(64, 4, 5), 256, 0, stream>>>(g);
  }

  // set A: r, w1, k, v, g projections (K=512)
  {
    GD<5> g;
    g.d[0] = {m5b + 0 * BTH, wpack + o_rW, rbuf, nullptr, nullptr, nullptr, 256, 512, 512, 512, 256, EP_NONE_BF16};
    g.d[1] = {m5b + 1 * BTH, wpack + o_wW1, wtmpb, nullptr, nullptr, nullptr, 128, 512, 512, 512, 128, EP_TANH_BF16};
    g.d[2] = {m5b + 2 * BTH, wpack + o_kW, kbuf, nullptr, nullptr, nullptr, 256, 512, 512, 512, 256, EP_NONE_BF16};
    g.d[3] = {m5b + 3 * BTH, wpack + o_vW, vbuf, nullptr, nullptr, nullptr, 512, 512, 512, 512, 512, EP_NONE_BF16};
    g.d[4] = {m5b + 4 * BTH, wpack + o_gW, gbuf, nullptr, nullptr, nullptr, 512, 512, 512, 512, 512, EP_NONE_BF16};
    mgemm<128, 128, 5><<<dim3(64, 4, 5), 256, 0, stream>>>(g);
  }

  // decay: ebuf = exp(-exp(wtmp @ w_W2^T + w_b)), K=64
  solo(wtmpb, wpack + o_wW2, ebuf, w_b, nullptr, nullptr,
       256, 64, 128, 64, 256, EP_EXPEXP_F32);

  wkv_pass1<<<2048, 128, 0, stream>>>(kbuf, ebuf, vbuf, Sl, Dp);
  wkv_scan<<<1024, 256, 0, stream>>>(Sl, Dp, Ss);
  wkv_pass3<<<2048, 128, 0, stream>>>(rbuf, kbuf, ebuf, vbuf, bonus, Ss,
                                      gbuf, gnorm_g, gnorm_b, obf16);

  // res = o @ o_W^T + x0
  solo(obf16, wpack + o_oW, res, nullptr, x0, nullptr,
       512, 512, 512, 512, 512, EP_RES_F32);

  ln1_kernel<<<BT_, 256, 0, stream>>>(res, ffn_g, ffn_b, hf);
  ffnmix_kernel<<<BT_, 256, 0, stream>>>(hf, fk_mu, fr_mu, mfk, mfr);

  // set C: fk (relu^2 -> kkb) and fr (-> frtmp), both K=512
  {
    GD<2> g;
    g.d[0] = {mfk, wpack + o_fkW, kkb, nullptr, nullptr, nullptr, 1024, 512, 512, 512, 1024, EP_RELU2_BF16};
    g.d[1] = {mfr, wpack + o_frW, frtmp, nullptr, nullptr, nullptr, 512, 512, 512, 512, 512, EP_NONE_F32};
    mgemm<128, 128, 2><<<dim3(64, 8, 2), 256, 0, stream>>>(g);
  }

  // out = res + sigmoid(frtmp) * (kk @ fv_W^T), K=1024
  solo(kkb, wpack + o_fvW, (float*)d_out, nullptr, res, frtmp,
       512, 1024, 1024, 1024, 512, EP_OUT2_F32);
}

// Round 17
// 321.817 us; speedup vs baseline: 1.1940x; 1.1940x over previous
//
#include <hip/hip_runtime.h>

// ---------------------------------------------------------------------------
// RWKV6 layer forward, MI355X. Round 17: gn_gate fusion retried with the
// round-16 defect removed — o values parked in LDS (oL[16][128]) instead of
// a register array stacked on live S[64] (VGPR 140->~90), and the mean/var
// reduction moved AFTER the scan loop (no serial shuffles in the scan).
// Everything else identical to round 16 / round 15.
// ---------------------------------------------------------------------------

#define DEVINL __device__ __forceinline__

constexpr int B_  = 8, T_ = 1024;
constexpr int BT_ = B_ * T_;          // 8192 tokens
constexpr float EPS_ = 1e-5f;
constexpr int CH_ = 16;               // WKV chunk length
constexpr int NC_ = T_ / CH_;         // 64 chunks per sequence

typedef __bf16 bf16x8 __attribute__((ext_vector_type(8)));
typedef float  f32x4  __attribute__((ext_vector_type(4)));

DEVINL unsigned short f2bs(float f) { // fp32 -> bf16 bits, RNE
  union { float f; unsigned int i; } c; c.f = f;
  unsigned int x = c.i;
  return (unsigned short)((x + 0x7fffu + ((x >> 16) & 1u)) >> 16);
}
DEVINL float b2f(unsigned short u) {
  union { unsigned int i; float f; } c; c.i = ((unsigned int)u) << 16; return c.f;
}

DEVINL float block_sum256(float v, float* sb) {
  for (int o = 32; o; o >>= 1) v += __shfl_down(v, o);
  int w = threadIdx.x >> 6;
  __syncthreads();
  if ((threadIdx.x & 63) == 0) sb[w] = v;
  __syncthreads();
  return sb[0] + sb[1] + sb[2] + sb[3];
}

// async global->LDS: 16B per lane, dest = ldsbase + lane*16 (wave-uniform base)
DEVINL void gload16(const unsigned short* gsrc, unsigned short* ldsbase) {
  __builtin_amdgcn_global_load_lds(
      (const __attribute__((address_space(1))) unsigned int*)gsrc,
      (__attribute__((address_space(3))) unsigned int*)ldsbase, 16, 0, 0);
}

// --------------------------- weight pack ------------------------------------
struct PackSeg { const float* src; int rows, cols, dst_rows; };
struct PackArgs { PackSeg s[12]; int base[13]; };

__global__ __launch_bounds__(256) void pack_kernel(PackArgs pa, unsigned short* dst)
{
  int i = blockIdx.x * 256 + threadIdx.x;
  if (i >= pa.base[12]) return;
  int k = 0;
  while (i >= pa.base[k + 1]) k++;
  int loc = i - pa.base[k];
  PackSeg s = pa.s[k];
  int r = loc / s.cols, c = loc - r * s.cols;
  float v = (r < s.rows) ? s.src[(size_t)r * s.cols + c] : 0.f;
  dst[i] = f2bs(v);
}

// --------------------------- LN kernels ------------------------------------
__global__ __launch_bounds__(256) void ln2_kernel(
    const float* __restrict__ x,
    const float* __restrict__ pg, const float* __restrict__ pb,
    const float* __restrict__ ag, const float* __restrict__ ab,
    float* __restrict__ x0, unsigned short* __restrict__ h)
{
  __shared__ float sb[4];
  size_t base = (size_t)blockIdx.x * 512;
  int tid = threadIdx.x;
  float v0 = x[base + tid], v1 = x[base + 256 + tid];
  float m = block_sum256(v0 + v1, sb) * (1.f / 512.f);
  float d0 = v0 - m, d1 = v1 - m;
  float var = block_sum256(d0 * d0 + d1 * d1, sb) * (1.f / 512.f);
  float rs = rsqrtf(var + EPS_);
  float a0 = d0 * rs * pg[tid]       + pb[tid];
  float a1 = d1 * rs * pg[tid + 256] + pb[tid + 256];
  x0[base + tid] = a0; x0[base + 256 + tid] = a1;
  float m2 = block_sum256(a0 + a1, sb) * (1.f / 512.f);
  float e0 = a0 - m2, e1 = a1 - m2;
  float var2 = block_sum256(e0 * e0 + e1 * e1, sb) * (1.f / 512.f);
  float rs2 = rsqrtf(var2 + EPS_);
  h[base + tid]       = f2bs(e0 * rs2 * ag[tid]       + ab[tid]);
  h[base + 256 + tid] = f2bs(e1 * rs2 * ag[tid + 256] + ab[tid + 256]);
}

__global__ __launch_bounds__(256) void ln1_kernel(
    const float* __restrict__ in,
    const float* __restrict__ g, const float* __restrict__ b,
    float* __restrict__ out)
{
  __shared__ float sb[4];
  size_t base = (size_t)blockIdx.x * 512;
  int tid = threadIdx.x;
  float v0 = in[base + tid], v1 = in[base + 256 + tid];
  float m = block_sum256(v0 + v1, sb) * (1.f / 512.f);
  float d0 = v0 - m, d1 = v1 - m;
  float var = block_sum256(d0 * d0 + d1 * d1, sb) * (1.f / 512.f);
  float rs = rsqrtf(var + EPS_);
  out[base + tid]       = d0 * rs * g[tid]       + b[tid];
  out[base + 256 + tid] = d1 * rs * g[tid + 256] + b[tid + 256];
}

// --------------------------- mix kernels ------------------------------------
__global__ __launch_bounds__(256) void ymix_kernel(
    const unsigned short* __restrict__ h, const float* __restrict__ mu,
    unsigned short* __restrict__ y, unsigned short* __restrict__ dl)
{
  int t = blockIdx.x, tid = threadIdx.x, tt = t & (T_ - 1);
  size_t base = (size_t)t * 512;
  for (int c = tid; c < 512; c += 256) {
    float cur  = b2f(h[base + c]);
    float prev = tt ? b2f(h[base - 512 + c]) : 0.f;
    float d = prev - cur;
    dl[base + c] = f2bs(d);
    y[base + c] = f2bs(cur + d * mu[c]);
  }
}

__global__ __launch_bounds__(256) void ffnmix_kernel(
    const float* __restrict__ hf, const float* __restrict__ fkmu,
    const float* __restrict__ frmu,
    unsigned short* __restrict__ mfk, unsigned short* __restrict__ mfr)
{
  int t = blockIdx.x, tid = threadIdx.x, tt = t & (T_ - 1);
  size_t base = (size_t)t * 512;
  for (int c = tid; c < 512; c += 256) {
    float cur  = hf[base + c];
    float prev = tt ? hf[base - 512 + c] : 0.f;
    float d = prev - cur;
    mfk[base + c] = f2bs(cur + d * fkmu[c]);
    mfr[base + c] = f2bs(cur + d * frmu[c]);
  }
}

// --------------------------- MFMA GEMM v8 -----------------------------------
enum { EP_NONE_F32 = 0, EP_NONE_BF16 = 1, EP_TANH_BF16 = 2, EP_EXPEXP_F32 = 3,
       EP_RES_F32 = 4, EP_RELU2_BF16 = 5, EP_OUT2_F32 = 6, EP_XMIX_BF16 = 7 };

struct GemmDesc {
  const unsigned short* A; const unsigned short* W; void* C;
  const void* bias; const void* aux1; const void* aux2;
  int N, K, lda, ldw, ldc, epi;
};
template <int NG> struct GD { GemmDesc d[NG]; };

template <int BM, int BN, int NG>
__global__ __launch_bounds__(256) void mgemm(GD<NG> p)
{
  GemmDesc dd = p.d[blockIdx.z];
  int n0 = blockIdx.y * BN;
  if (n0 >= dd.N) return;
  int m0 = blockIdx.x * BM;
  constexpr int MFR = BM / 32, NFR = BN / 32;
  constexpr int AIS = BM / 64, WIS = BN / 64;      // gload issues per wave
  constexpr int NLD = AIS + WIS;                   // loads per tile per wave
  __shared__ unsigned short LDSbuf[3 * (BM + BN) * 32];
  unsigned short* AsBase = LDSbuf;                 // [3][BM*32]
  unsigned short* WsBase = LDSbuf + 3 * BM * 32;   // [3][BN*32]
  int tid = threadIdx.x, lane = tid & 63, wid = tid >> 6;
  int wm = wid >> 1, wn = wid & 1, lrow = lane & 15, lkg = lane >> 4;
  int XL = (lrow & 3) ^ ((lrow >> 2) & 3);         // read-side XOR term

  const unsigned short* aSrc[AIS]; int aOff[AIS];
#pragma unroll
  for (int i = 0; i < AIS; i++) {
    int u = i * 256 + wid * 64 + lane;
    int row = u >> 2;
    int kg = (u & 3) ^ (row & 3) ^ ((row >> 2) & 3);
    aSrc[i] = dd.A + (size_t)(m0 + row) * dd.lda + kg * 8;
    aOff[i] = (i * 256 + wid * 64) * 8;
  }
  const unsigned short* wSrc[WIS]; int wOff[WIS];
#pragma unroll
  for (int i = 0; i < WIS; i++) {
    int u = i * 256 + wid * 64 + lane;
    int row = u >> 2;
    int kg = (u & 3) ^ (row & 3) ^ ((row >> 2) & 3);
    wSrc[i] = dd.W + (size_t)(n0 + row) * dd.ldw + kg * 8;
    wOff[i] = (i * 256 + wid * 64) * 8;
  }

  f32x4 acc[MFR][NFR];
#pragma unroll
  for (int mf = 0; mf < MFR; mf++)
#pragma unroll
    for (int nf = 0; nf < NFR; nf++) acc[mf][nf] = (f32x4){0.f, 0.f, 0.f, 0.f};

  int nt = dd.K >> 5;
#pragma unroll
  for (int i = 0; i < AIS; i++) gload16(aSrc[i], AsBase + aOff[i]);
#pragma unroll
  for (int i = 0; i < WIS; i++) gload16(wSrc[i], WsBase + wOff[i]);
  if (nt > 1) {
#pragma unroll
    for (int i = 0; i < AIS; i++) gload16(aSrc[i] + 32, AsBase + BM * 32 + aOff[i]);
#pragma unroll
    for (int i = 0; i < WIS; i++) gload16(wSrc[i] + 32, WsBase + BN * 32 + wOff[i]);
  }

  int cur = 0, pf = 2;                    // compute buffer / next fill buffer
  for (int t = 0; t < nt; ++t) {
    if (t + 2 < nt) {
      int kb2 = (t + 2) << 5;
      unsigned short* aD = AsBase + pf * (BM * 32);
      unsigned short* wD = WsBase + pf * (BN * 32);
#pragma unroll
      for (int i = 0; i < AIS; i++) gload16(aSrc[i] + kb2, aD + aOff[i]);
#pragma unroll
      for (int i = 0; i < WIS; i++) gload16(wSrc[i] + kb2, wD + wOff[i]);
      pf = (pf == 2) ? 0 : pf + 1;
      if constexpr (NLD == 4) asm volatile("s_waitcnt vmcnt(8)" ::: "memory");
      else                    asm volatile("s_waitcnt vmcnt(4)" ::: "memory");
    } else if (t + 1 < nt) {
      if constexpr (NLD == 4) asm volatile("s_waitcnt vmcnt(4)" ::: "memory");
      else                    asm volatile("s_waitcnt vmcnt(2)" ::: "memory");
    } else {
      asm volatile("s_waitcnt vmcnt(0)" ::: "memory");
    }
    __builtin_amdgcn_sched_barrier(0);
    __builtin_amdgcn_s_barrier();         // tile t's LDS complete, all waves

    const unsigned short* AsB = AsBase + cur * (BM * 32);
    const unsigned short* WsB = WsBase + cur * (BN * 32);
    bf16x8 bfrag[NFR];
#pragma unroll
    for (int nf = 0; nf < NFR; nf++) {
      int row = (wn * NFR + nf) * 16 + lrow;
      bfrag[nf] = *(const bf16x8*)&WsB[(row * 4 + (lkg ^ XL)) * 8];
    }
#pragma unroll
    for (int mf = 0; mf < MFR; mf++) {
      int row = (wm * MFR + mf) * 16 + lrow;
      bf16x8 afrag = *(const bf16x8*)&AsB[(row * 4 + (lkg ^ XL)) * 8];
#pragma unroll
      for (int nf = 0; nf < NFR; nf++)
        acc[mf][nf] = __builtin_amdgcn_mfma_f32_16x16x32_bf16(
            bfrag[nf], afrag, acc[mf][nf], 0, 0, 0);   // D rows = n
    }
    __builtin_amdgcn_sched_barrier(0);
    __builtin_amdgcn_s_barrier();         // all waves done reading cur
    cur = (cur == 2) ? 0 : cur + 1;
  }

  bool bf16out = (dd.epi == EP_NONE_BF16 || dd.epi == EP_TANH_BF16 ||
                  dd.epi == EP_RELU2_BF16 || dd.epi == EP_XMIX_BF16);
  if (!bf16out) {
#pragma unroll
    for (int mf = 0; mf < MFR; mf++) {
#pragma unroll
      for (int nf = 0; nf < NFR; nf++) {
        int m  = m0 + wm * (MFR * 16) + mf * 16 + lrow;
        int nb = n0 + wn * (NFR * 16) + nf * 16 + lkg * 4;
        size_t off = (size_t)m * dd.ldc + nb;
        float c0 = acc[mf][nf][0], c1 = acc[mf][nf][1];
        float c2 = acc[mf][nf][2], c3 = acc[mf][nf][3];
        switch (dd.epi) {
          case EP_NONE_F32: {
            f32x4 v = {c0, c1, c2, c3};
            *(f32x4*)((float*)dd.C + off) = v; break;
          }
          case EP_EXPEXP_F32: {
            const float* bi = (const float*)dd.bias;
            f32x4 v = {expf(-expf(c0 + bi[nb + 0])), expf(-expf(c1 + bi[nb + 1])),
                       expf(-expf(c2 + bi[nb + 2])), expf(-expf(c3 + bi[nb + 3]))};
            *(f32x4*)((float*)dd.C + off) = v; break;
          }
          case EP_RES_F32: {
            f32x4 a = *(const f32x4*)((const float*)dd.aux1 + off);
            f32x4 v = {c0 + a[0], c1 + a[1], c2 + a[2], c3 + a[3]};
            *(f32x4*)((float*)dd.C + off) = v; break;
          }
          case EP_OUT2_F32: {
            f32x4 rs = *(const f32x4*)((const float*)dd.aux1 + off);
            f32x4 fr = *(const f32x4*)((const float*)dd.aux2 + off);
            f32x4 v = {rs[0] + (1.f / (1.f + expf(-fr[0]))) * c0,
                       rs[1] + (1.f / (1.f + expf(-fr[1]))) * c1,
                       rs[2] + (1.f / (1.f + expf(-fr[2]))) * c2,
                       rs[3] + (1.f / (1.f + expf(-fr[3]))) * c3};
            *(f32x4*)((float*)dd.C + off) = v; break;
          }
        }
      }
    }
    return;
  }

  __syncthreads();                         // staging buffers fully dead
  unsigned short* Cs = LDSbuf;             // BM*BN shorts
#pragma unroll
  for (int mf = 0; mf < MFR; mf++) {
#pragma unroll
    for (int nf = 0; nf < NFR; nf++) {
      int mloc = wm * (MFR * 16) + mf * 16 + lrow;
      int nbl  = wn * (NFR * 16) + nf * 16 + lkg * 4;
      int m = m0 + mloc, nb = n0 + nbl;
      size_t off = (size_t)m * dd.ldc + nb;
      float c0 = acc[mf][nf][0], c1 = acc[mf][nf][1];
      float c2 = acc[mf][nf][2], c3 = acc[mf][nf][3];
      uint2 u;
      switch (dd.epi) {
        case EP_NONE_BF16:
          u.x = f2bs(c0) | ((unsigned)f2bs(c1) << 16);
          u.y = f2bs(c2) | ((unsigned)f2bs(c3) << 16);
          break;
        case EP_TANH_BF16:
          u.x = f2bs(tanhf(c0)) | ((unsigned)f2bs(tanhf(c1)) << 16);
          u.y = f2bs(tanhf(c2)) | ((unsigned)f2bs(tanhf(c3)) << 16);
          break;
        case EP_RELU2_BF16: {
          c0 = fmaxf(c0, 0.f); c1 = fmaxf(c1, 0.f);
          c2 = fmaxf(c2, 0.f); c3 = fmaxf(c3, 0.f);
          u.x = f2bs(c0 * c0) | ((unsigned)f2bs(c1 * c1) << 16);
          u.y = f2bs(c2 * c2) | ((unsigned)f2bs(c3 * c3) << 16);
          break;
        }
        default: { // EP_XMIX_BF16
          const float* bi = (const float*)dd.bias;
          uint2 hv = *(const uint2*)((const unsigned short*)dd.aux1 + off);
          uint2 dv = *(const uint2*)((const unsigned short*)dd.aux2 + off);
          const unsigned short* hu = (const unsigned short*)&hv;
          const unsigned short* du = (const unsigned short*)&dv;
          float r0 = b2f(hu[0]) + b2f(du[0]) * (c0 + bi[nb + 0]);
          float r1 = b2f(hu[1]) + b2f(du[1]) * (c1 + bi[nb + 1]);
          float r2 = b2f(hu[2]) + b2f(du[2]) * (c2 + bi[nb + 2]);
          float r3 = b2f(hu[3]) + b2f(du[3]) * (c3 + bi[nb + 3]);
          u.x = f2bs(r0) | ((unsigned)f2bs(r1) << 16);
          u.y = f2bs(r2) | ((unsigned)f2bs(r3) << 16);
          break;
        }
      }
      int col4 = (nbl >> 2) ^ ((mloc & 7) << 1);   // even XOR: keeps 16B pairs
      *(uint2*)&Cs[mloc * BN + col4 * 4] = u;
    }
  }
  __syncthreads();
  constexpr int JW = BN / 8;               // 16B units per row
  constexpr int UNITS = BM * JW;
  for (int it = tid; it < UNITS; it += 256) {
    int row = it / JW, j = it - row * JW;
    int e = (row & 7) << 1;
    int4 vv = *(const int4*)&Cs[row * BN + (((2 * j) ^ e) << 2)];
    *(int4*)((unsigned short*)dd.C + (size_t)(m0 + row) * dd.ldc + n0 + j * 8) = vv;
  }
}

// --------------------------- WKV 3-pass chunked scan (CH=16) ----------------
__global__ __launch_bounds__(128) void wkv_pass1(
    const unsigned short* __restrict__ k, const float* __restrict__ ew,
    const unsigned short* __restrict__ v, unsigned short* __restrict__ Sl,
    float* __restrict__ Dp)
{
  __shared__ float kL[CH_][64], eL[CH_][64];
  int blk = blockIdx.x;
  int c = blk & (NC_ - 1), bh = blk >> 6;
  int b = bh >> 2, hh = bh & 3;
  int tid = threadIdx.x;
  size_t tbase = (size_t)b * T_ + (size_t)c * CH_;
  for (int idx = tid; idx < CH_ * 64; idx += 128) {
    int s = idx >> 6, j = idx & 63;
    size_t g = (tbase + s) * 256 + hh * 64 + j;
    kL[s][j] = b2f(k[g]); eL[s][j] = ew[g];
  }
  __syncthreads();
  float S[64];
#pragma unroll
  for (int j = 0; j < 64; j++) S[j] = 0.f;
  for (int s = 0; s < CH_; s++) {
    float vv = b2f(v[(tbase + s) * 512 + hh * 128 + tid]);
    const float4* e4p = (const float4*)&eL[s][0];
    const float4* k4p = (const float4*)&kL[s][0];
#pragma unroll
    for (int q = 0; q < 16; q++) {
      float4 e4 = e4p[q], k4 = k4p[q];
      S[4 * q + 0] = e4.x * S[4 * q + 0] + k4.x * vv;
      S[4 * q + 1] = e4.y * S[4 * q + 1] + k4.y * vv;
      S[4 * q + 2] = e4.z * S[4 * q + 2] + k4.z * vv;
      S[4 * q + 3] = e4.w * S[4 * q + 3] + k4.w * vv;
    }
  }
  size_t sbase = (size_t)blk * 8192;
#pragma unroll
  for (int j = 0; j < 64; j++) Sl[sbase + j * 128 + tid] = f2bs(S[j]);
  if (tid < 64) {
    float d = 1.f;
    for (int s = 0; s < CH_; s++) d *= eL[s][tid];
    Dp[(size_t)blk * 64 + tid] = d;
  }
}

__global__ __launch_bounds__(256) void wkv_scan(
    const unsigned short* __restrict__ Sl, const float* __restrict__ Dp,
    unsigned short* __restrict__ Ss)
{
  int e = blockIdx.x * 256 + threadIdx.x;
  int bh = e >> 13; int kv = e & 8191; int j = kv >> 7;
  float run = 0.f;
  for (int c = 0; c < NC_; c++) {
    size_t base = (size_t)bh * NC_ + c;
    Ss[base * 8192 + kv] = f2bs(run);
    run = Dp[base * 64 + j] * run + b2f(Sl[base * 8192 + kv]);
  }
}

// pass3: replay chunk; rbk in-kernel; GroupNorm+swish gate fused via LDS
// (oL[16][128]) with post-loop reduction. Emits bf16 gated output.
__global__ __launch_bounds__(128) void wkv_pass3(
    const unsigned short* __restrict__ r, const unsigned short* __restrict__ k,
    const float* __restrict__ ew, const unsigned short* __restrict__ v,
    const float* __restrict__ bonus, const unsigned short* __restrict__ Ss,
    const unsigned short* __restrict__ g,
    const float* __restrict__ gg, const float* __restrict__ gb,
    unsigned short* __restrict__ obf)
{
  __shared__ float rL[CH_][64], kL[CH_][64], eL[CH_][64], rbL[CH_];
  __shared__ float oL[CH_][128];
  __shared__ float mh[CH_], rsd[CH_];
  int blk = blockIdx.x;
  int c = blk & (NC_ - 1), bh = blk >> 6;
  int b = bh >> 2, hh = bh & 3;
  int tid = threadIdx.x;
  size_t tbase = (size_t)b * T_ + (size_t)c * CH_;
  for (int idx = tid; idx < CH_ * 64; idx += 128) {
    int s = idx >> 6, j = idx & 63;
    size_t gg2 = (tbase + s) * 256 + hh * 64 + j;
    rL[s][j] = b2f(r[gg2]); kL[s][j] = b2f(k[gg2]); eL[s][j] = ew[gg2];
  }
  __syncthreads();
  {
    // rbk: 8 lanes per token s
    int s = tid >> 3, part = tid & 7;
    float acc = 0.f;
#pragma unroll
    for (int q = 0; q < 8; q++) {
      int j = part * 8 + q;
      acc += rL[s][j] * kL[s][j] * bonus[hh * 64 + j];
    }
    acc += __shfl_down(acc, 4);
    acc += __shfl_down(acc, 2);
    acc += __shfl_down(acc, 1);
    if (part == 0) rbL[s] = acc;
  }
  __syncthreads();
  float S[64];
  size_t sbase = (size_t)blk * 8192;
#pragma unroll
  for (int j = 0; j < 64; j++) S[j] = b2f(Ss[sbase + j * 128 + tid]);
  for (int s = 0; s < CH_; s++) {
    float vv = b2f(v[(tbase + s) * 512 + hh * 128 + tid]);
    float o = rbL[s] * vv;
    const float4* r4p = (const float4*)&rL[s][0];
    const float4* e4p = (const float4*)&eL[s][0];
    const float4* k4p = (const float4*)&kL[s][0];
#pragma unroll
    for (int q = 0; q < 16; q++) {
      float4 r4 = r4p[q], e4 = e4p[q], k4 = k4p[q];
      o += r4.x * S[4 * q + 0] + r4.y * S[4 * q + 1]
         + r4.z * S[4 * q + 2] + r4.w * S[4 * q + 3];
      S[4 * q + 0] = e4.x * S[4 * q + 0] + k4.x * vv;
      S[4 * q + 1] = e4.y * S[4 * q + 1] + k4.y * vv;
      S[4 * q + 2] = e4.z * S[4 * q + 2] + k4.z * vv;
      S[4 * q + 3] = e4.w * S[4 * q + 3] + k4.w * vv;
    }
    oL[s][tid] = o;
  }
  __syncthreads();
  {
    // post-loop GroupNorm reduction: 8 threads per token, 16 channels each.
    int s = tid >> 3, part = tid & 7;
    float sm = 0.f, sq = 0.f;
#pragma unroll
    for (int q = 0; q < 16; q++) {
      float o = oL[s][part * 16 + q];
      sm += o; sq += o * o;
    }
    sm += __shfl_down(sm, 4); sq += __shfl_down(sq, 4);
    sm += __shfl_down(sm, 2); sq += __shfl_down(sq, 2);
    sm += __shfl_down(sm, 1); sq += __shfl_down(sq, 1);
    if (part == 0) {
      float m = sm * (1.f / 128.f);
      float var = sq * (1.f / 128.f) - m * m;
      mh[s] = m; rsd[s] = rsqrtf(var + EPS_);
    }
  }
  __syncthreads();
  int ch = hh * 128 + tid;
  float gam = gg[ch], bet = gb[ch];
  for (int s = 0; s < CH_; s++) {
    float nrm = (oL[s][tid] - mh[s]) * rsd[s];
    float gv = b2f(g[(tbase + s) * 512 + ch]);
    float sw = gv * (1.f / (1.f + expf(-gv)));
    obf[(tbase + s) * 512 + ch] = f2bs((nrm * gam + bet) * sw);
  }
}

// ---------------------------------------------------------------------------
extern "C" void kernel_launch(void* const* d_in, const int* in_sizes, int n_in,
                              void* d_out, int out_size, void* d_ws, size_t ws_size,
                              hipStream_t stream) {
  (void)in_sizes; (void)n_in; (void)out_size; (void)ws_size;
  const float* x        = (const float*)d_in[0];
  const float* pre_g    = (const float*)d_in[1];
  const float* pre_b    = (const float*)d_in[2];
  const float* attn_g   = (const float*)d_in[3];
  const float* attn_b   = (const float*)d_in[4];
  const float* ffn_g    = (const float*)d_in[5];
  const float* ffn_b    = (const float*)d_in[6];
  const float* xproj_mu = (const float*)d_in[7];
  const float* xproj_w1 = (const float*)d_in[8];
  const float* xproj_w2 = (const float*)d_in[9];
  const float* x_bias   = (const float*)d_in[10];
  const float* r_W      = (const float*)d_in[11];
  const float* w_W1     = (const float*)d_in[12];
  const float* w_W2     = (const float*)d_in[13];
  const float* w_b      = (const float*)d_in[14];
  const float* k_W      = (const float*)d_in[15];
  const float* v_W      = (const float*)d_in[16];
  const float* g_W      = (const float*)d_in[17];
  const float* bonus    = (const float*)d_in[18];
  const float* gnorm_g  = (const float*)d_in[19];
  const float* gnorm_b  = (const float*)d_in[20];
  const float* o_W      = (const float*)d_in[21];
  const float* fk_mu    = (const float*)d_in[22];
  const float* fk_W     = (const float*)d_in[23];
  const float* fv_W     = (const float*)d_in[24];
  const float* fr_mu    = (const float*)d_in[25];
  const float* fr_W     = (const float*)d_in[26];

  const size_t BTH = (size_t)BT_ * 512;  // 4,194,304
  size_t cur = 0;
  auto alloc = [&](size_t bytes) { void* p = (char*)d_ws + cur; cur += (bytes + 255) & ~(size_t)255; return p; };
  float*          x0    = (float*)alloc(BTH * 4);
  unsigned short* hbufb = (unsigned short*)alloc(BTH * 2);
  unsigned short* m5b   = (unsigned short*)alloc(5 * BTH * 2);   // 40MB
  unsigned short* rbuf  = (unsigned short*)alloc((size_t)BT_ * 256 * 4);
  unsigned short* kbuf  = (unsigned short*)alloc((size_t)BT_ * 256 * 4);
  float*          ebuf  = (float*)alloc((size_t)BT_ * 256 * 4);
  unsigned short* vbuf  = (unsigned short*)alloc(BTH * 4);
  unsigned short* gbuf  = (unsigned short*)alloc(BTH * 4);
  unsigned short* wtmpb = (unsigned short*)alloc((size_t)BT_ * 128 * 2);
  unsigned short* Sl    = (unsigned short*)alloc((size_t)2048 * 8192 * 2);
  unsigned short* Ss    = (unsigned short*)alloc((size_t)2048 * 8192 * 2);
  float*          Dp    = (float*)alloc((size_t)2048 * 64 * 4);
  float*          res   = (float*)alloc(BTH * 4);
  unsigned short* wpack = (unsigned short*)alloc((size_t)2621440 * 2);
  // aliases (occupant dead before writer runs):
  unsigned short* ybufb = rbuf;
  unsigned short* dlb   = vbuf;
  unsigned short* z5b   = gbuf;
  unsigned short* obf16 = (unsigned short*)ebuf;   // ebuf dead after pass3
  float*          hf    = x0;
  unsigned short* mfk   = rbuf;
  unsigned short* mfr   = kbuf;
  unsigned short* kkb   = Sl;
  float*          frtmp = (float*)vbuf;

  PackArgs pa;
  int off = 0, seg = 0;
  auto addseg = [&](const float* src, int rows, int cols, int dst_rows) {
    pa.s[seg] = {src, rows, cols, dst_rows};
    pa.base[seg] = off; off += dst_rows * cols; seg++;
  };
  addseg(xproj_w1, 160, 512, 192);   int o_w1p = pa.base[0];
  addseg(w_W1,      64, 512, 128);   int o_wW1 = pa.base[1];
  addseg(r_W,      256, 512, 256);   int o_rW  = pa.base[2];
  addseg(k_W,      256, 512, 256);   int o_kW  = pa.base[3];
  addseg(v_W,      512, 512, 512);   int o_vW  = pa.base[4];
  addseg(g_W,      512, 512, 512);   int o_gW  = pa.base[5];
  addseg(o_W,      512, 512, 512);   int o_oW  = pa.base[6];
  addseg(fk_W,    1024, 512, 1024);  int o_fkW = pa.base[7];
  addseg(fv_W,     512, 1024, 512);  int o_fvW = pa.base[8];
  addseg(fr_W,     512, 512, 512);   int o_frW = pa.base[9];
  addseg(w_W2,     256, 64, 256);    int o_wW2 = pa.base[10];
  addseg(xproj_w2, 512, 160, 512);   int o_xw2 = pa.base[11];
  pa.base[12] = off;

  pack_kernel<<<(off + 255) / 256, 256, 0, stream>>>(pa, wpack);
  ln2_kernel<<<BT_, 256, 0, stream>>>(x, pre_g, pre_b, attn_g, attn_b, x0, hbufb);
  ymix_kernel<<<BT_, 256, 0, stream>>>(hbufb, xproj_mu, ybufb, dlb);

  auto solo = [&](const unsigned short* A, const unsigned short* W, void* C,
                  const void* bias, const void* a1, const void* a2,
                  int N, int K, int lda, int ldw, int ldc, int epi) {
    GD<1> g; g.d[0] = {A, W, C, bias, a1, a2, N, K, lda, ldw, ldc, epi};
    mgemm<64, 64, 1><<<dim3(128, (N + 63) / 64, 1), 256, 0, stream>>>(g);
  };

  // z5 = tanh(Y @ W1p^T), N=192
  solo(ybufb, wpack + o_w1p, z5b, nullptr, nullptr, nullptr,
       192, 512, 512, 512, 192, EP_TANH_BF16);

  // xmix as grouped GEMM (K=32), LDS-staged EP_XMIX_BF16 epilogue
  {
    GD<5> g;
    for (int n = 0; n < 5; n++)
      g.d[n] = {z5b + n * 32, wpack + o_xw2 + n * 32, m5b + (size_t)n * BTH,
                x_bias + n * 512, hbufb, dlb, 512, 32, 192, 160, 512, EP_XMIX_BF16};
    mgemm<128, 128, 5><<<dim3(64, 4, 5), 256, 0, stream>>>(g);
  }

  // set A: r, w1, k, v, g projections (K=512)
  {
    GD<5> g;
    g.d[0] = {m5b + 0 * BTH, wpack + o_rW, rbuf, nullptr, nullptr, nullptr, 256, 512, 512, 512, 256, EP_NONE_BF16};
    g.d[1] = {m5b + 1 * BTH, wpack + o_wW1, wtmpb, nullptr, nullptr, nullptr, 128, 512, 512, 512, 128, EP_TANH_BF16};
    g.d[2] = {m5b + 2 * BTH, wpack + o_kW, kbuf, nullptr, nullptr, nullptr, 256, 512, 512, 512, 256, EP_NONE_BF16};
    g.d[3] = {m5b + 3 * BTH, wpack + o_vW, vbuf, nullptr, nullptr, nullptr, 512, 512, 512, 512, 512, EP_NONE_BF16};
    g.d[4] = {m5b + 4 * BTH, wpack + o_gW, gbuf, nullptr, nullptr, nullptr, 512, 512, 512, 512, 512, EP_NONE_BF16};
    mgemm<128, 128, 5><<<dim3(64, 4, 5), 256, 0, stream>>>(g);
  }

  // decay: ebuf = exp(-exp(wtmp @ w_W2^T + w_b)), K=64
  solo(wtmpb, wpack + o_wW2, ebuf, w_b, nullptr, nullptr,
       256, 64, 128, 64, 256, EP_EXPEXP_F32);

  wkv_pass1<<<2048, 128, 0, stream>>>(kbuf, ebuf, vbuf, Sl, Dp);
  wkv_scan<<<1024, 256, 0, stream>>>(Sl, Dp, Ss);
  wkv_pass3<<<2048, 128, 0, stream>>>(rbuf, kbuf, ebuf, vbuf, bonus, Ss,
                                      gbuf, gnorm_g, gnorm_b, obf16);

  // res = o @ o_W^T + x0
  solo(obf16, wpack + o_oW, res, nullptr, x0, nullptr,
       512, 512, 512, 512, 512, EP_RES_F32);

  ln1_kernel<<<BT_, 256, 0, stream>>>(res, ffn_g, ffn_b, hf);
  ffnmix_kernel<<<BT_, 256, 0, stream>>>(hf, fk_mu, fr_mu, mfk, mfr);

  // set C: fk (relu^2 -> kkb) and fr (-> frtmp), both K=512
  {
    GD<2> g;
    g.d[0] = {mfk, wpack + o_fkW, kkb, nullptr, nullptr, nullptr, 1024, 512, 512, 512, 1024, EP_RELU2_BF16};
    g.d[1] = {mfr, wpack + o_frW, frtmp, nullptr, nullptr, nullptr, 512, 512, 512, 512, 512, EP_NONE_F32};
    mgemm<128, 128, 2><<<dim3(64, 8, 2), 256, 0, stream>>>(g);
  }

  // out = res + sigmoid(frtmp) * (kk @ fv_W^T), K=1024
  solo(kkb, wpack + o_fvW, (float*)d_out, nullptr, res, frtmp,
       512, 1024, 1024, 1024, 512, EP_OUT2_F32);
}

// Round 18
// 304.126 us; speedup vs baseline: 1.2634x; 1.0582x over previous
//
#include <hip/hip_runtime.h>

// ---------------------------------------------------------------------------
// RWKV6 layer forward, MI355X. Round 18: exact revert to round 15 (best,
// 309.1us). GEMM v8 (3-buf distance-2, coalesced XOR staging, LDS-staged
// bf16 epilogue); rbk fused in wkv_pass3; gn_gate separate (both fusion
// variants regressed: regs->VGPR 140, LDS->occupancy 22%).
// ---------------------------------------------------------------------------

#define DEVINL __device__ __forceinline__

constexpr int B_  = 8, T_ = 1024;
constexpr int BT_ = B_ * T_;          // 8192 tokens
constexpr float EPS_ = 1e-5f;
constexpr int CH_ = 16;               // WKV chunk length
constexpr int NC_ = T_ / CH_;         // 64 chunks per sequence

typedef __bf16 bf16x8 __attribute__((ext_vector_type(8)));
typedef float  f32x4  __attribute__((ext_vector_type(4)));

DEVINL unsigned short f2bs(float f) { // fp32 -> bf16 bits, RNE
  union { float f; unsigned int i; } c; c.f = f;
  unsigned int x = c.i;
  return (unsigned short)((x + 0x7fffu + ((x >> 16) & 1u)) >> 16);
}
DEVINL float b2f(unsigned short u) {
  union { unsigned int i; float f; } c; c.i = ((unsigned int)u) << 16; return c.f;
}

DEVINL float block_sum256(float v, float* sb) {
  for (int o = 32; o; o >>= 1) v += __shfl_down(v, o);
  int w = threadIdx.x >> 6;
  __syncthreads();
  if ((threadIdx.x & 63) == 0) sb[w] = v;
  __syncthreads();
  return sb[0] + sb[1] + sb[2] + sb[3];
}

// async global->LDS: 16B per lane, dest = ldsbase + lane*16 (wave-uniform base)
DEVINL void gload16(const unsigned short* gsrc, unsigned short* ldsbase) {
  __builtin_amdgcn_global_load_lds(
      (const __attribute__((address_space(1))) unsigned int*)gsrc,
      (__attribute__((address_space(3))) unsigned int*)ldsbase, 16, 0, 0);
}

// --------------------------- weight pack ------------------------------------
struct PackSeg { const float* src; int rows, cols, dst_rows; };
struct PackArgs { PackSeg s[12]; int base[13]; };

__global__ __launch_bounds__(256) void pack_kernel(PackArgs pa, unsigned short* dst)
{
  int i = blockIdx.x * 256 + threadIdx.x;
  if (i >= pa.base[12]) return;
  int k = 0;
  while (i >= pa.base[k + 1]) k++;
  int loc = i - pa.base[k];
  PackSeg s = pa.s[k];
  int r = loc / s.cols, c = loc - r * s.cols;
  float v = (r < s.rows) ? s.src[(size_t)r * s.cols + c] : 0.f;
  dst[i] = f2bs(v);
}

// --------------------------- LN kernels ------------------------------------
__global__ __launch_bounds__(256) void ln2_kernel(
    const float* __restrict__ x,
    const float* __restrict__ pg, const float* __restrict__ pb,
    const float* __restrict__ ag, const float* __restrict__ ab,
    float* __restrict__ x0, unsigned short* __restrict__ h)
{
  __shared__ float sb[4];
  size_t base = (size_t)blockIdx.x * 512;
  int tid = threadIdx.x;
  float v0 = x[base + tid], v1 = x[base + 256 + tid];
  float m = block_sum256(v0 + v1, sb) * (1.f / 512.f);
  float d0 = v0 - m, d1 = v1 - m;
  float var = block_sum256(d0 * d0 + d1 * d1, sb) * (1.f / 512.f);
  float rs = rsqrtf(var + EPS_);
  float a0 = d0 * rs * pg[tid]       + pb[tid];
  float a1 = d1 * rs * pg[tid + 256] + pb[tid + 256];
  x0[base + tid] = a0; x0[base + 256 + tid] = a1;
  float m2 = block_sum256(a0 + a1, sb) * (1.f / 512.f);
  float e0 = a0 - m2, e1 = a1 - m2;
  float var2 = block_sum256(e0 * e0 + e1 * e1, sb) * (1.f / 512.f);
  float rs2 = rsqrtf(var2 + EPS_);
  h[base + tid]       = f2bs(e0 * rs2 * ag[tid]       + ab[tid]);
  h[base + 256 + tid] = f2bs(e1 * rs2 * ag[tid + 256] + ab[tid + 256]);
}

__global__ __launch_bounds__(256) void ln1_kernel(
    const float* __restrict__ in,
    const float* __restrict__ g, const float* __restrict__ b,
    float* __restrict__ out)
{
  __shared__ float sb[4];
  size_t base = (size_t)blockIdx.x * 512;
  int tid = threadIdx.x;
  float v0 = in[base + tid], v1 = in[base + 256 + tid];
  float m = block_sum256(v0 + v1, sb) * (1.f / 512.f);
  float d0 = v0 - m, d1 = v1 - m;
  float var = block_sum256(d0 * d0 + d1 * d1, sb) * (1.f / 512.f);
  float rs = rsqrtf(var + EPS_);
  out[base + tid]       = d0 * rs * g[tid]       + b[tid];
  out[base + 256 + tid] = d1 * rs * g[tid + 256] + b[tid + 256];
}

// --------------------------- mix kernels ------------------------------------
__global__ __launch_bounds__(256) void ymix_kernel(
    const unsigned short* __restrict__ h, const float* __restrict__ mu,
    unsigned short* __restrict__ y, unsigned short* __restrict__ dl)
{
  int t = blockIdx.x, tid = threadIdx.x, tt = t & (T_ - 1);
  size_t base = (size_t)t * 512;
  for (int c = tid; c < 512; c += 256) {
    float cur  = b2f(h[base + c]);
    float prev = tt ? b2f(h[base - 512 + c]) : 0.f;
    float d = prev - cur;
    dl[base + c] = f2bs(d);
    y[base + c] = f2bs(cur + d * mu[c]);
  }
}

__global__ __launch_bounds__(256) void ffnmix_kernel(
    const float* __restrict__ hf, const float* __restrict__ fkmu,
    const float* __restrict__ frmu,
    unsigned short* __restrict__ mfk, unsigned short* __restrict__ mfr)
{
  int t = blockIdx.x, tid = threadIdx.x, tt = t & (T_ - 1);
  size_t base = (size_t)t * 512;
  for (int c = tid; c < 512; c += 256) {
    float cur  = hf[base + c];
    float prev = tt ? hf[base - 512 + c] : 0.f;
    float d = prev - cur;
    mfk[base + c] = f2bs(cur + d * fkmu[c]);
    mfr[base + c] = f2bs(cur + d * frmu[c]);
  }
}

// --------------------------- MFMA GEMM v8 -----------------------------------
enum { EP_NONE_F32 = 0, EP_NONE_BF16 = 1, EP_TANH_BF16 = 2, EP_EXPEXP_F32 = 3,
       EP_RES_F32 = 4, EP_RELU2_BF16 = 5, EP_OUT2_F32 = 6, EP_XMIX_BF16 = 7 };

struct GemmDesc {
  const unsigned short* A; const unsigned short* W; void* C;
  const void* bias; const void* aux1; const void* aux2;
  int N, K, lda, ldw, ldc, epi;
};
template <int NG> struct GD { GemmDesc d[NG]; };

template <int BM, int BN, int NG>
__global__ __launch_bounds__(256) void mgemm(GD<NG> p)
{
  GemmDesc dd = p.d[blockIdx.z];
  int n0 = blockIdx.y * BN;
  if (n0 >= dd.N) return;
  int m0 = blockIdx.x * BM;
  constexpr int MFR = BM / 32, NFR = BN / 32;
  constexpr int AIS = BM / 64, WIS = BN / 64;      // gload issues per wave
  constexpr int NLD = AIS + WIS;                   // loads per tile per wave
  __shared__ unsigned short LDSbuf[3 * (BM + BN) * 32];
  unsigned short* AsBase = LDSbuf;                 // [3][BM*32]
  unsigned short* WsBase = LDSbuf + 3 * BM * 32;   // [3][BN*32]
  int tid = threadIdx.x, lane = tid & 63, wid = tid >> 6;
  int wm = wid >> 1, wn = wid & 1, lrow = lane & 15, lkg = lane >> 4;
  int XL = (lrow & 3) ^ ((lrow >> 2) & 3);         // read-side XOR term

  const unsigned short* aSrc[AIS]; int aOff[AIS];
#pragma unroll
  for (int i = 0; i < AIS; i++) {
    int u = i * 256 + wid * 64 + lane;
    int row = u >> 2;
    int kg = (u & 3) ^ (row & 3) ^ ((row >> 2) & 3);
    aSrc[i] = dd.A + (size_t)(m0 + row) * dd.lda + kg * 8;
    aOff[i] = (i * 256 + wid * 64) * 8;
  }
  const unsigned short* wSrc[WIS]; int wOff[WIS];
#pragma unroll
  for (int i = 0; i < WIS; i++) {
    int u = i * 256 + wid * 64 + lane;
    int row = u >> 2;
    int kg = (u & 3) ^ (row & 3) ^ ((row >> 2) & 3);
    wSrc[i] = dd.W + (size_t)(n0 + row) * dd.ldw + kg * 8;
    wOff[i] = (i * 256 + wid * 64) * 8;
  }

  f32x4 acc[MFR][NFR];
#pragma unroll
  for (int mf = 0; mf < MFR; mf++)
#pragma unroll
    for (int nf = 0; nf < NFR; nf++) acc[mf][nf] = (f32x4){0.f, 0.f, 0.f, 0.f};

  int nt = dd.K >> 5;
#pragma unroll
  for (int i = 0; i < AIS; i++) gload16(aSrc[i], AsBase + aOff[i]);
#pragma unroll
  for (int i = 0; i < WIS; i++) gload16(wSrc[i], WsBase + wOff[i]);
  if (nt > 1) {
#pragma unroll
    for (int i = 0; i < AIS; i++) gload16(aSrc[i] + 32, AsBase + BM * 32 + aOff[i]);
#pragma unroll
    for (int i = 0; i < WIS; i++) gload16(wSrc[i] + 32, WsBase + BN * 32 + wOff[i]);
  }

  int cur = 0, pf = 2;                    // compute buffer / next fill buffer
  for (int t = 0; t < nt; ++t) {
    if (t + 2 < nt) {
      int kb2 = (t + 2) << 5;
      unsigned short* aD = AsBase + pf * (BM * 32);
      unsigned short* wD = WsBase + pf * (BN * 32);
#pragma unroll
      for (int i = 0; i < AIS; i++) gload16(aSrc[i] + kb2, aD + aOff[i]);
#pragma unroll
      for (int i = 0; i < WIS; i++) gload16(wSrc[i] + kb2, wD + wOff[i]);
      pf = (pf == 2) ? 0 : pf + 1;
      if constexpr (NLD == 4) asm volatile("s_waitcnt vmcnt(8)" ::: "memory");
      else                    asm volatile("s_waitcnt vmcnt(4)" ::: "memory");
    } else if (t + 1 < nt) {
      if constexpr (NLD == 4) asm volatile("s_waitcnt vmcnt(4)" ::: "memory");
      else                    asm volatile("s_waitcnt vmcnt(2)" ::: "memory");
    } else {
      asm volatile("s_waitcnt vmcnt(0)" ::: "memory");
    }
    __builtin_amdgcn_sched_barrier(0);
    __builtin_amdgcn_s_barrier();         // tile t's LDS complete, all waves

    const unsigned short* AsB = AsBase + cur * (BM * 32);
    const unsigned short* WsB = WsBase + cur * (BN * 32);
    bf16x8 bfrag[NFR];
#pragma unroll
    for (int nf = 0; nf < NFR; nf++) {
      int row = (wn * NFR + nf) * 16 + lrow;
      bfrag[nf] = *(const bf16x8*)&WsB[(row * 4 + (lkg ^ XL)) * 8];
    }
#pragma unroll
    for (int mf = 0; mf < MFR; mf++) {
      int row = (wm * MFR + mf) * 16 + lrow;
      bf16x8 afrag = *(const bf16x8*)&AsB[(row * 4 + (lkg ^ XL)) * 8];
#pragma unroll
      for (int nf = 0; nf < NFR; nf++)
        acc[mf][nf] = __builtin_amdgcn_mfma_f32_16x16x32_bf16(
            bfrag[nf], afrag, acc[mf][nf], 0, 0, 0);   // D rows = n
    }
    __builtin_amdgcn_sched_barrier(0);
    __builtin_amdgcn_s_barrier();         // all waves done reading cur
    cur = (cur == 2) ? 0 : cur + 1;
  }

  bool bf16out = (dd.epi == EP_NONE_BF16 || dd.epi == EP_TANH_BF16 ||
                  dd.epi == EP_RELU2_BF16 || dd.epi == EP_XMIX_BF16);
  if (!bf16out) {
#pragma unroll
    for (int mf = 0; mf < MFR; mf++) {
#pragma unroll
      for (int nf = 0; nf < NFR; nf++) {
        int m  = m0 + wm * (MFR * 16) + mf * 16 + lrow;
        int nb = n0 + wn * (NFR * 16) + nf * 16 + lkg * 4;
        size_t off = (size_t)m * dd.ldc + nb;
        float c0 = acc[mf][nf][0], c1 = acc[mf][nf][1];
        float c2 = acc[mf][nf][2], c3 = acc[mf][nf][3];
        switch (dd.epi) {
          case EP_NONE_F32: {
            f32x4 v = {c0, c1, c2, c3};
            *(f32x4*)((float*)dd.C + off) = v; break;
          }
          case EP_EXPEXP_F32: {
            const float* bi = (const float*)dd.bias;
            f32x4 v = {expf(-expf(c0 + bi[nb + 0])), expf(-expf(c1 + bi[nb + 1])),
                       expf(-expf(c2 + bi[nb + 2])), expf(-expf(c3 + bi[nb + 3]))};
            *(f32x4*)((float*)dd.C + off) = v; break;
          }
          case EP_RES_F32: {
            f32x4 a = *(const f32x4*)((const float*)dd.aux1 + off);
            f32x4 v = {c0 + a[0], c1 + a[1], c2 + a[2], c3 + a[3]};
            *(f32x4*)((float*)dd.C + off) = v; break;
          }
          case EP_OUT2_F32: {
            f32x4 rs = *(const f32x4*)((const float*)dd.aux1 + off);
            f32x4 fr = *(const f32x4*)((const float*)dd.aux2 + off);
            f32x4 v = {rs[0] + (1.f / (1.f + expf(-fr[0]))) * c0,
                       rs[1] + (1.f / (1.f + expf(-fr[1]))) * c1,
                       rs[2] + (1.f / (1.f + expf(-fr[2]))) * c2,
                       rs[3] + (1.f / (1.f + expf(-fr[3]))) * c3};
            *(f32x4*)((float*)dd.C + off) = v; break;
          }
        }
      }
    }
    return;
  }

  __syncthreads();                         // staging buffers fully dead
  unsigned short* Cs = LDSbuf;             // BM*BN shorts
#pragma unroll
  for (int mf = 0; mf < MFR; mf++) {
#pragma unroll
    for (int nf = 0; nf < NFR; nf++) {
      int mloc = wm * (MFR * 16) + mf * 16 + lrow;
      int nbl  = wn * (NFR * 16) + nf * 16 + lkg * 4;
      int m = m0 + mloc, nb = n0 + nbl;
      size_t off = (size_t)m * dd.ldc + nb;
      float c0 = acc[mf][nf][0], c1 = acc[mf][nf][1];
      float c2 = acc[mf][nf][2], c3 = acc[mf][nf][3];
      uint2 u;
      switch (dd.epi) {
        case EP_NONE_BF16:
          u.x = f2bs(c0) | ((unsigned)f2bs(c1) << 16);
          u.y = f2bs(c2) | ((unsigned)f2bs(c3) << 16);
          break;
        case EP_TANH_BF16:
          u.x = f2bs(tanhf(c0)) | ((unsigned)f2bs(tanhf(c1)) << 16);
          u.y = f2bs(tanhf(c2)) | ((unsigned)f2bs(tanhf(c3)) << 16);
          break;
        case EP_RELU2_BF16: {
          c0 = fmaxf(c0, 0.f); c1 = fmaxf(c1, 0.f);
          c2 = fmaxf(c2, 0.f); c3 = fmaxf(c3, 0.f);
          u.x = f2bs(c0 * c0) | ((unsigned)f2bs(c1 * c1) << 16);
          u.y = f2bs(c2 * c2) | ((unsigned)f2bs(c3 * c3) << 16);
          break;
        }
        default: { // EP_XMIX_BF16
          const float* bi = (const float*)dd.bias;
          uint2 hv = *(const uint2*)((const unsigned short*)dd.aux1 + off);
          uint2 dv = *(const uint2*)((const unsigned short*)dd.aux2 + off);
          const unsigned short* hu = (const unsigned short*)&hv;
          const unsigned short* du = (const unsigned short*)&dv;
          float r0 = b2f(hu[0]) + b2f(du[0]) * (c0 + bi[nb + 0]);
          float r1 = b2f(hu[1]) + b2f(du[1]) * (c1 + bi[nb + 1]);
          float r2 = b2f(hu[2]) + b2f(du[2]) * (c2 + bi[nb + 2]);
          float r3 = b2f(hu[3]) + b2f(du[3]) * (c3 + bi[nb + 3]);
          u.x = f2bs(r0) | ((unsigned)f2bs(r1) << 16);
          u.y = f2bs(r2) | ((unsigned)f2bs(r3) << 16);
          break;
        }
      }
      int col4 = (nbl >> 2) ^ ((mloc & 7) << 1);   // even XOR: keeps 16B pairs
      *(uint2*)&Cs[mloc * BN + col4 * 4] = u;
    }
  }
  __syncthreads();
  constexpr int JW = BN / 8;               // 16B units per row
  constexpr int UNITS = BM * JW;
  for (int it = tid; it < UNITS; it += 256) {
    int row = it / JW, j = it - row * JW;
    int e = (row & 7) << 1;
    int4 vv = *(const int4*)&Cs[row * BN + (((2 * j) ^ e) << 2)];
    *(int4*)((unsigned short*)dd.C + (size_t)(m0 + row) * dd.ldc + n0 + j * 8) = vv;
  }
}

// --------------------------- WKV 3-pass chunked scan (CH=16) ----------------
__global__ __launch_bounds__(128) void wkv_pass1(
    const unsigned short* __restrict__ k, const float* __restrict__ ew,
    const unsigned short* __restrict__ v, unsigned short* __restrict__ Sl,
    float* __restrict__ Dp)
{
  __shared__ float kL[CH_][64], eL[CH_][64];
  int blk = blockIdx.x;
  int c = blk & (NC_ - 1), bh = blk >> 6;
  int b = bh >> 2, hh = bh & 3;
  int tid = threadIdx.x;
  size_t tbase = (size_t)b * T_ + (size_t)c * CH_;
  for (int idx = tid; idx < CH_ * 64; idx += 128) {
    int s = idx >> 6, j = idx & 63;
    size_t g = (tbase + s) * 256 + hh * 64 + j;
    kL[s][j] = b2f(k[g]); eL[s][j] = ew[g];
  }
  __syncthreads();
  float S[64];
#pragma unroll
  for (int j = 0; j < 64; j++) S[j] = 0.f;
  for (int s = 0; s < CH_; s++) {
    float vv = b2f(v[(tbase + s) * 512 + hh * 128 + tid]);
    const float4* e4p = (const float4*)&eL[s][0];
    const float4* k4p = (const float4*)&kL[s][0];
#pragma unroll
    for (int q = 0; q < 16; q++) {
      float4 e4 = e4p[q], k4 = k4p[q];
      S[4 * q + 0] = e4.x * S[4 * q + 0] + k4.x * vv;
      S[4 * q + 1] = e4.y * S[4 * q + 1] + k4.y * vv;
      S[4 * q + 2] = e4.z * S[4 * q + 2] + k4.z * vv;
      S[4 * q + 3] = e4.w * S[4 * q + 3] + k4.w * vv;
    }
  }
  size_t sbase = (size_t)blk * 8192;
#pragma unroll
  for (int j = 0; j < 64; j++) Sl[sbase + j * 128 + tid] = f2bs(S[j]);
  if (tid < 64) {
    float d = 1.f;
    for (int s = 0; s < CH_; s++) d *= eL[s][tid];
    Dp[(size_t)blk * 64 + tid] = d;
  }
}

__global__ __launch_bounds__(256) void wkv_scan(
    const unsigned short* __restrict__ Sl, const float* __restrict__ Dp,
    unsigned short* __restrict__ Ss)
{
  int e = blockIdx.x * 256 + threadIdx.x;
  int bh = e >> 13; int kv = e & 8191; int j = kv >> 7;
  float run = 0.f;
  for (int c = 0; c < NC_; c++) {
    size_t base = (size_t)bh * NC_ + c;
    Ss[base * 8192 + kv] = f2bs(run);
    run = Dp[base * 64 + j] * run + b2f(Sl[base * 8192 + kv]);
  }
}

// pass3: replay chunk, emit o; rbk (bonus dot) computed in-kernel from LDS.
__global__ __launch_bounds__(128) void wkv_pass3(
    const unsigned short* __restrict__ r, const unsigned short* __restrict__ k,
    const float* __restrict__ ew, const unsigned short* __restrict__ v,
    const float* __restrict__ bonus, const unsigned short* __restrict__ Ss,
    float* __restrict__ o)
{
  __shared__ float rL[CH_][64], kL[CH_][64], eL[CH_][64], rbL[CH_];
  int blk = blockIdx.x;
  int c = blk & (NC_ - 1), bh = blk >> 6;
  int b = bh >> 2, hh = bh & 3;
  int tid = threadIdx.x;
  size_t tbase = (size_t)b * T_ + (size_t)c * CH_;
  for (int idx = tid; idx < CH_ * 64; idx += 128) {
    int s = idx >> 6, j = idx & 63;
    size_t g = (tbase + s) * 256 + hh * 64 + j;
    rL[s][j] = b2f(r[g]); kL[s][j] = b2f(k[g]); eL[s][j] = ew[g];
  }
  __syncthreads();
  {
    // rbk: 8 lanes per token s; each sums 8 j's, then shuffle-reduce.
    int s = tid >> 3, part = tid & 7;      // s in [0,16), part in [0,8)
    float acc = 0.f;
#pragma unroll
    for (int q = 0; q < 8; q++) {
      int j = part * 8 + q;
      acc += rL[s][j] * kL[s][j] * bonus[hh * 64 + j];
    }
    acc += __shfl_down(acc, 4);
    acc += __shfl_down(acc, 2);
    acc += __shfl_down(acc, 1);
    if (part == 0) rbL[s] = acc;
  }
  __syncthreads();
  float S[64];
  size_t sbase = (size_t)blk * 8192;
#pragma unroll
  for (int j = 0; j < 64; j++) S[j] = b2f(Ss[sbase + j * 128 + tid]);
  for (int s = 0; s < CH_; s++) {
    float vv = b2f(v[(tbase + s) * 512 + hh * 128 + tid]);
    float oa = rbL[s] * vv;
    const float4* r4p = (const float4*)&rL[s][0];
    const float4* e4p = (const float4*)&eL[s][0];
    const float4* k4p = (const float4*)&kL[s][0];
#pragma unroll
    for (int q = 0; q < 16; q++) {
      float4 r4 = r4p[q], e4 = e4p[q], k4 = k4p[q];
      oa += r4.x * S[4 * q + 0] + r4.y * S[4 * q + 1]
          + r4.z * S[4 * q + 2] + r4.w * S[4 * q + 3];
      S[4 * q + 0] = e4.x * S[4 * q + 0] + k4.x * vv;
      S[4 * q + 1] = e4.y * S[4 * q + 1] + k4.y * vv;
      S[4 * q + 2] = e4.z * S[4 * q + 2] + k4.z * vv;
      S[4 * q + 3] = e4.w * S[4 * q + 3] + k4.w * vv;
    }
    o[(tbase + s) * 512 + hh * 128 + tid] = oa;
  }
}

// --------------------------- groupnorm + swish gate -------------------------
__global__ __launch_bounds__(256) void gn_gate_kernel(
    const float* __restrict__ o, const unsigned short* __restrict__ g,
    const float* __restrict__ gg, const float* __restrict__ gb,
    unsigned short* __restrict__ obf)
{
  __shared__ float ov[512], ps[64], qs[64], mh[4], vh[4];
  int t = blockIdx.x, tid = threadIdx.x;
  size_t base = (size_t)t * 512;
  ov[tid] = o[base + tid]; ov[tid + 256] = o[base + 256 + tid];
  __syncthreads();
  if (tid < 64) {
    int hh = tid >> 4, sg = tid & 15;
    const float* p = &ov[hh * 128 + sg * 8];
    float s = 0.f, q = 0.f;
    for (int i = 0; i < 8; i++) { s += p[i]; q += p[i] * p[i]; }
    ps[tid] = s; qs[tid] = q;
  }
  __syncthreads();
  if (tid < 4) {
    float s = 0.f, q = 0.f;
    for (int i = 0; i < 16; i++) { s += ps[tid * 16 + i]; q += qs[tid * 16 + i]; }
    float m = s * (1.f / 128.f);
    mh[tid] = m; vh[tid] = q * (1.f / 128.f) - m * m;
  }
  __syncthreads();
  for (int c = tid; c < 512; c += 256) {
    int hh = c >> 7;
    float nrm = (ov[c] - mh[hh]) * rsqrtf(vh[hh] + EPS_);
    float gv = b2f(g[base + c]);
    float sw = gv * (1.f / (1.f + expf(-gv)));
    obf[base + c] = f2bs((nrm * gg[c] + gb[c]) * sw);
  }
}

// ---------------------------------------------------------------------------
extern "C" void kernel_launch(void* const* d_in, const int* in_sizes, int n_in,
                              void* d_out, int out_size, void* d_ws, size_t ws_size,
                              hipStream_t stream) {
  (void)in_sizes; (void)n_in; (void)out_size; (void)ws_size;
  const float* x        = (const float*)d_in[0];
  const float* pre_g    = (const float*)d_in[1];
  const float* pre_b    = (const float*)d_in[2];
  const float* attn_g   = (const float*)d_in[3];
  const float* attn_b   = (const float*)d_in[4];
  const float* ffn_g    = (const float*)d_in[5];
  const float* ffn_b    = (const float*)d_in[6];
  const float* xproj_mu = (const float*)d_in[7];
  const float* xproj_w1 = (const float*)d_in[8];
  const float* xproj_w2 = (const float*)d_in[9];
  const float* x_bias   = (const float*)d_in[10];
  const float* r_W      = (const float*)d_in[11];
  const float* w_W1     = (const float*)d_in[12];
  const float* w_W2     = (const float*)d_in[13];
  const float* w_b      = (const float*)d_in[14];
  const float* k_W      = (const float*)d_in[15];
  const float* v_W      = (const float*)d_in[16];
  const float* g_W      = (const float*)d_in[17];
  const float* bonus    = (const float*)d_in[18];
  const float* gnorm_g  = (const float*)d_in[19];
  const float* gnorm_b  = (const float*)d_in[20];
  const float* o_W      = (const float*)d_in[21];
  const float* fk_mu    = (const float*)d_in[22];
  const float* fk_W     = (const float*)d_in[23];
  const float* fv_W     = (const float*)d_in[24];
  const float* fr_mu    = (const float*)d_in[25];
  const float* fr_W     = (const float*)d_in[26];

  const size_t BTH = (size_t)BT_ * 512;  // 4,194,304
  size_t cur = 0;
  auto alloc = [&](size_t bytes) { void* p = (char*)d_ws + cur; cur += (bytes + 255) & ~(size_t)255; return p; };
  float*          x0    = (float*)alloc(BTH * 4);
  unsigned short* hbufb = (unsigned short*)alloc(BTH * 2);
  unsigned short* m5b   = (unsigned short*)alloc(5 * BTH * 2);   // 40MB
  unsigned short* rbuf  = (unsigned short*)alloc((size_t)BT_ * 256 * 4);
  unsigned short* kbuf  = (unsigned short*)alloc((size_t)BT_ * 256 * 4);
  float*          ebuf  = (float*)alloc((size_t)BT_ * 256 * 4);
  unsigned short* vbuf  = (unsigned short*)alloc(BTH * 4);
  unsigned short* gbuf  = (unsigned short*)alloc(BTH * 4);
  unsigned short* wtmpb = (unsigned short*)alloc((size_t)BT_ * 128 * 2);
  unsigned short* Sl    = (unsigned short*)alloc((size_t)2048 * 8192 * 2);
  unsigned short* Ss    = (unsigned short*)alloc((size_t)2048 * 8192 * 2);
  float*          Dp    = (float*)alloc((size_t)2048 * 64 * 4);
  float*          res   = (float*)alloc(BTH * 4);
  unsigned short* wpack = (unsigned short*)alloc((size_t)2621440 * 2);
  // aliases (occupant dead before writer runs):
  unsigned short* ybufb = rbuf;
  unsigned short* dlb   = vbuf;
  unsigned short* z5b   = gbuf;
  float*          obuf  = (float*)m5b;
  unsigned short* obf16 = (unsigned short*)ebuf;
  float*          hf    = x0;
  unsigned short* mfk   = rbuf;
  unsigned short* mfr   = kbuf;
  unsigned short* kkb   = Sl;
  float*          frtmp = (float*)vbuf;

  PackArgs pa;
  int off = 0, seg = 0;
  auto addseg = [&](const float* src, int rows, int cols, int dst_rows) {
    pa.s[seg] = {src, rows, cols, dst_rows};
    pa.base[seg] = off; off += dst_rows * cols; seg++;
  };
  addseg(xproj_w1, 160, 512, 192);   int o_w1p = pa.base[0];
  addseg(w_W1,      64, 512, 128);   int o_wW1 = pa.base[1];
  addseg(r_W,      256, 512, 256);   int o_rW  = pa.base[2];
  addseg(k_W,      256, 512, 256);   int o_kW  = pa.base[3];
  addseg(v_W,      512, 512, 512);   int o_vW  = pa.base[4];
  addseg(g_W,      512, 512, 512);   int o_gW  = pa.base[5];
  addseg(o_W,      512, 512, 512);   int o_oW  = pa.base[6];
  addseg(fk_W,    1024, 512, 1024);  int o_fkW = pa.base[7];
  addseg(fv_W,     512, 1024, 512);  int o_fvW = pa.base[8];
  addseg(fr_W,     512, 512, 512);   int o_frW = pa.base[9];
  addseg(w_W2,     256, 64, 256);    int o_wW2 = pa.base[10];
  addseg(xproj_w2, 512, 160, 512);   int o_xw2 = pa.base[11];
  pa.base[12] = off;

  pack_kernel<<<(off + 255) / 256, 256, 0, stream>>>(pa, wpack);
  ln2_kernel<<<BT_, 256, 0, stream>>>(x, pre_g, pre_b, attn_g, attn_b, x0, hbufb);
  ymix_kernel<<<BT_, 256, 0, stream>>>(hbufb, xproj_mu, ybufb, dlb);

  auto solo = [&](const unsigned short* A, const unsigned short* W, void* C,
                  const void* bias, const void* a1, const void* a2,
                  int N, int K, int lda, int ldw, int ldc, int epi) {
    GD<1> g; g.d[0] = {A, W, C, bias, a1, a2, N, K, lda, ldw, ldc, epi};
    mgemm<64, 64, 1><<<dim3(128, (N + 63) / 64, 1), 256, 0, stream>>>(g);
  };

  // z5 = tanh(Y @ W1p^T), N=192
  solo(ybufb, wpack + o_w1p, z5b, nullptr, nullptr, nullptr,
       192, 512, 512, 512, 192, EP_TANH_BF16);

  // xmix as grouped GEMM (K=32), LDS-staged EP_XMIX_BF16 epilogue
  {
    GD<5> g;
    for (int n = 0; n < 5; n++)
      g.d[n] = {z5b + n * 32, wpack + o_xw2 + n * 32, m5b + (size_t)n * BTH,
                x_bias + n * 512, hbufb, dlb, 512, 32, 192, 160, 512, EP_XMIX_BF16};
    mgemm<128, 128, 5><<<dim3(64, 4, 5), 256, 0, stream>>>(g);
  }

  // set A: r, w1, k, v, g projections (K=512)
  {
    GD<5> g;
    g.d[0] = {m5b + 0 * BTH, wpack + o_rW, rbuf, nullptr, nullptr, nullptr, 256, 512, 512, 512, 256, EP_NONE_BF16};
    g.d[1] = {m5b + 1 * BTH, wpack + o_wW1, wtmpb, nullptr, nullptr, nullptr, 128, 512, 512, 512, 128, EP_TANH_BF16};
    g.d[2] = {m5b + 2 * BTH, wpack + o_kW, kbuf, nullptr, nullptr, nullptr, 256, 512, 512, 512, 256, EP_NONE_BF16};
    g.d[3] = {m5b + 3 * BTH, wpack + o_vW, vbuf, nullptr, nullptr, nullptr, 512, 512, 512, 512, 512, EP_NONE_BF16};
    g.d[4] = {m5b + 4 * BTH, wpack + o_gW, gbuf, nullptr, nullptr, nullptr, 512, 512, 512, 512, 512, EP_NONE_BF16};
    mgemm<128, 128, 5><<<dim3(64, 4, 5), 256, 0, stream>>>(g);
  }

  // decay: ebuf = exp(-exp(wtmp @ w_W2^T + w_b)), K=64
  solo(wtmpb, wpack + o_wW2, ebuf, w_b, nullptr, nullptr,
       256, 64, 128, 64, 256, EP_EXPEXP_F32);

  wkv_pass1<<<2048, 128, 0, stream>>>(kbuf, ebuf, vbuf, Sl, Dp);
  wkv_scan<<<1024, 256, 0, stream>>>(Sl, Dp, Ss);
  wkv_pass3<<<2048, 128, 0, stream>>>(rbuf, kbuf, ebuf, vbuf, bonus, Ss, obuf);

  gn_gate_kernel<<<BT_, 256, 0, stream>>>(obuf, gbuf, gnorm_g, gnorm_b, obf16);

  // res = o @ o_W^T + x0
  solo(obf16, wpack + o_oW, res, nullptr, x0, nullptr,
       512, 512, 512, 512, 512, EP_RES_F32);

  ln1_kernel<<<BT_, 256, 0, stream>>>(res, ffn_g, ffn_b, hf);
  ffnmix_kernel<<<BT_, 256, 0, stream>>>(hf, fk_mu, fr_mu, mfk, mfr);

  // set C: fk (relu^2 -> kkb) and fr (-> frtmp), both K=512
  {
    GD<2> g;
    g.d[0] = {mfk, wpack + o_fkW, kkb, nullptr, nullptr, nullptr, 1024, 512, 512, 512, 1024, EP_RELU2_BF16};
    g.d[1] = {mfr, wpack + o_frW, frtmp, nullptr, nullptr, nullptr, 512, 512, 512, 512, 512, EP_NONE_F32};
    mgemm<128, 128, 2><<<dim3(64, 8, 2), 256, 0, stream>>>(g);
  }

  // out = res + sigmoid(frtmp) * (kk @ fv_W^T), K=1024
  solo(kkb, wpack + o_fvW, (float*)d_out, nullptr, res, frtmp,
       512, 1024, 1024, 1024, 512, EP_OUT2_F32);
}